// Round 8
// baseline (2271.797 us; speedup 1.0000x reference)
//
#include <hip/hip_runtime.h>
#include <math.h>

#define EMB 128
#define NH 8
#define DH 16
#define HID 256
#define NODE 1000
#define PATCH 196
#define NKEY (NODE + PATCH)   // 1196
#define BB 8
#define POMO 1000
#define KT 32                  // attention key tile
#define SCH 4                  // key-split chunks
#define CKEYS 300              // keys per chunk (last = 296)
#define RTILES 32              // 32-row tiles
#define TROWS 32

// partial buffers alias d_out (8M floats):
// pacc: [b][tile][chunk][row32][h][16] = 8*32*4*32*8*16 = 4,194,304 floats
// pl  : [b][tile][chunk][h][row32]     = 8*32*4*8*32    =   262,144 floats
#define PACC_FLOATS 4194304L

__device__ __forceinline__ float tanh10(float x) {
    float e = __expf(2.0f * x);
    return 10.0f * (1.0f - 2.0f / (e + 1.0f));
}

// ---------------- hypernet stage 1: pref -> mid[15] -------------------------
__global__ __launch_bounds__(256) void hyper_mid_kernel(
    const float* __restrict__ pref,
    const float* __restrict__ fc1_w, const float* __restrict__ fc1_b,
    const float* __restrict__ fc2_w, const float* __restrict__ fc2_b,
    const float* __restrict__ fc3_w, const float* __restrict__ fc3_b,
    float* __restrict__ gmid)
{
    __shared__ float h1[HID];
    __shared__ float h2[HID];
    int t = threadIdx.x;
    float p0 = pref[0], p1 = pref[1], p2 = pref[2];
    h1[t] = fc1_b[t] + p0 * fc1_w[t * 3 + 0] + p1 * fc1_w[t * 3 + 1] + p2 * fc1_w[t * 3 + 2];
    __syncthreads();
    {
        float s = fc2_b[t];
        const float4* w4 = (const float4*)(fc2_w + t * HID);
        const float4* h4 = (const float4*)h1;
        for (int j = 0; j < HID / 4; ++j) {
            float4 w = w4[j], x = h4[j];
            s += x.x * w.x + x.y * w.y + x.z * w.z + x.w * w.w;
        }
        h2[t] = s;
    }
    __syncthreads();
    if (t < 15) {
        float s = fc3_b[t];
        const float4* w4 = (const float4*)(fc3_w + t * HID);
        const float4* h4 = (const float4*)h2;
        for (int j = 0; j < HID / 4; ++j) {
            float4 w = w4[j], x = h4[j];
            s += x.x * w.x + x.y * w.y + x.z * w.z + x.w * w.w;
        }
        gmid[t] = s;
    }
}

// ---------------- hypernet stage 2: mid -> 5 weight matrices ----------------
__global__ __launch_bounds__(256) void hyper_expand_kernel(
    const float* __restrict__ gmid,
    const float* __restrict__ wqf, const float* __restrict__ wql,
    const float* __restrict__ wk,  const float* __restrict__ wv,
    const float* __restrict__ wc,  float* __restrict__ W5)
{
    int id = blockIdx.x;                 // 40 blocks: 5 mats x 8 segments
    int mat = id >> 3;
    int x0 = (id & 7) * 2048 + threadIdx.x * 8;
    const float* w = (mat == 0) ? wqf : (mat == 1) ? wql : (mat == 2) ? wk : (mat == 3) ? wv : wc;
    float m0 = gmid[mat * 3 + 0], m1 = gmid[mat * 3 + 1], m2 = gmid[mat * 3 + 2];
    float* dst = W5 + mat * EMB * EMB;
    #pragma unroll
    for (int i = 0; i < 8; ++i) {
        int x = x0 + i;
        dst[x] = m0 * w[x * 3 + 0] + m1 * w[x * 3 + 1] + m2 * w[x * 3 + 2];
    }
}

// ---------------- K,V projection of encoded_nodes ---------------------------
__global__ __launch_bounds__(256) void kv_proj_kernel(
    const float* __restrict__ nodes, const float* __restrict__ W5,
    float* __restrict__ Kb, float* __restrict__ Vb)
{
    __shared__ float xs[32][EMB];
    int t = threadIdx.x;
    long r0 = (long)blockIdx.x * 32;            // over BB*NKEY = 9568 (299*32 exact)
    const float4* s4 = (const float4*)(nodes + r0 * EMB);
    float4* x4p = (float4*)&xs[0][0];
    for (int i = t; i < 32 * EMB / 4; i += 256) x4p[i] = s4[i];
    __syncthreads();
    int o = t;
    const float* W = (o < EMB) ? (W5 + 2 * EMB * EMB + o * EMB)
                               : (W5 + 3 * EMB * EMB + (o - EMB) * EMB);
    float acc[32];
    #pragma unroll
    for (int r = 0; r < 32; ++r) acc[r] = 0.f;
    for (int e = 0; e < EMB; e += 4) {
        float4 w4 = *(const float4*)&W[e];
        #pragma unroll
        for (int r = 0; r < 32; ++r) {
            float4 x4 = *(const float4*)&xs[r][e];
            acc[r] += x4.x * w4.x + x4.y * w4.y + x4.z * w4.z + x4.w * w4.w;
        }
    }
    float* dst = (o < EMB) ? (Kb + r0 * EMB + o) : (Vb + r0 * EMB + (o - EMB));
    #pragma unroll
    for (int r = 0; r < 32; ++r) dst[(long)r * EMB] = acc[r];
}

// ---------------- Q projection: q1@Wqf.T + last@Wql.T -----------------------
__global__ __launch_bounds__(256) void q_proj_kernel(
    const float* __restrict__ q1, const float* __restrict__ lastn,
    const float* __restrict__ W5, float* __restrict__ Qb)
{
    __shared__ float xa[32][EMB];
    __shared__ float xb[32][EMB];
    int t = threadIdx.x;
    long r0 = (long)blockIdx.x * 32;            // over 8000 (250*32 exact)
    const float4* a4 = (const float4*)(q1 + r0 * EMB);
    const float4* b4 = (const float4*)(lastn + r0 * EMB);
    float4* xap = (float4*)&xa[0][0];
    float4* xbp = (float4*)&xb[0][0];
    for (int i = t; i < 32 * EMB / 4; i += 256) { xap[i] = a4[i]; xbp[i] = b4[i]; }
    __syncthreads();
    int o = t & 127;
    int rbase = (t >> 7) * 16;
    const float* Wf = W5 + 0 * EMB * EMB + o * EMB;
    const float* Wl = W5 + 1 * EMB * EMB + o * EMB;
    float acc[16];
    #pragma unroll
    for (int r = 0; r < 16; ++r) acc[r] = 0.f;
    for (int e = 0; e < EMB; e += 4) {
        float4 wf = *(const float4*)&Wf[e];
        float4 wl = *(const float4*)&Wl[e];
        #pragma unroll
        for (int r = 0; r < 16; ++r) {
            float4 va = *(const float4*)&xa[rbase + r][e];
            float4 vb = *(const float4*)&xb[rbase + r][e];
            acc[r] += va.x * wf.x + va.y * wf.y + va.z * wf.z + va.w * wf.w
                    + vb.x * wl.x + vb.y * wl.y + vb.z * wl.z + vb.w * wl.w;
        }
    }
    #pragma unroll
    for (int r = 0; r < 16; ++r) Qb[(r0 + rbase + r) * EMB + o] = acc[r];
}

// ---------------- fused masked MHA, key-split, no-max-shift, KT=32 ----------
// grid (8, 32, 4): x=b (XCD-aligned), y=32-row tile, z=key chunk. 1024 blocks
// = exactly 4 blocks/CU (one residency round, no scheduling tail).
// block 128: h = t>>4, rr = t&15; thread owns rows {2rr, 2rr+1} (R=2, the
// proven no-spill point: q32+acc32+transients ~ <=128 VGPR).
// Mask loaded per-j4 (transient regs); node/patch boundary via jm window.
__global__ __launch_bounds__(128, 2) void attn_split_kernel(
    const float* __restrict__ Kb, const float* __restrict__ Vb,
    const float* __restrict__ Qb, const float* __restrict__ mask,
    float* __restrict__ pacc, float* __restrict__ pl)
{
    __shared__ float ks[KT][EMB];   // 16 KB
    __shared__ float vs[KT][EMB];   // 16 KB
    int t = threadIdx.x;
    int b = blockIdx.x, tile = blockIdx.y, c = blockIdx.z;
    int rr = t & 15, h = t >> 4;
    int row0 = tile * TROWS + rr * 2;
    bool active = (row0 < POMO);
    int qrow = active ? row0 : (POMO - 2);     // clamped; stores guarded
    int kstart = c * CKEYS;
    int kend = kstart + CKEYS; if (kend > NKEY) kend = NKEY;

    float q0[DH], q1r[DH];
    {
        const float4* qp0 = (const float4*)(Qb + ((long)b * POMO + qrow) * EMB + h * DH);
        const float4* qp1 = (const float4*)(Qb + ((long)b * POMO + qrow + 1) * EMB + h * DH);
        #pragma unroll
        for (int i = 0; i < 4; ++i) {
            float4 v = qp0[i];   // pre-scale by 1/sqrt(16): s = q.k + mask
            q0[4*i+0] = v.x*0.25f; q0[4*i+1] = v.y*0.25f;
            q0[4*i+2] = v.z*0.25f; q0[4*i+3] = v.w*0.25f;
            float4 w = qp1[i];
            q1r[4*i+0] = w.x*0.25f; q1r[4*i+1] = w.y*0.25f;
            q1r[4*i+2] = w.z*0.25f; q1r[4*i+3] = w.w*0.25f;
        }
    }
    float acc0[DH], acc1[DH];
    #pragma unroll
    for (int i = 0; i < DH; ++i) { acc0[i] = 0.f; acc1[i] = 0.f; }
    float l0 = 0.f, l1 = 0.f;

    const float4* ksrc = (const float4*)(Kb + (long)b * NKEY * EMB);
    const float4* vsrc = (const float4*)(Vb + (long)b * NKEY * EMB);
    const int max4 = NKEY * (EMB / 4) - 1;
    const float* mrow0 = mask + ((long)b * POMO + qrow) * NODE;
    const float* mrow1 = mrow0 + NODE;
    const float4 z4 = make_float4(0.f, 0.f, 0.f, 0.f);

    for (int t0 = kstart; t0 < kend; t0 += KT) {
        int valid = kend - t0; if (valid > KT) valid = KT;   // 32, 12 or 8
        __syncthreads();
        {   // stage K,V tile via registers (L2-friendly), clamped source
            float4* kd = (float4*)&ks[0][0];
            float4* vd = (float4*)&vs[0][0];
            int base4 = t0 * (EMB / 4);
            #pragma unroll
            for (int u = 0; u < 8; ++u) {
                int i = t + u * 128;
                int src = base4 + i; if (src > max4) src = max4;
                kd[i] = ksrc[src];
                vd[i] = vsrc[src];
            }
        }
        __syncthreads();

        // float4 groups of keys that carry mask: j4 < jm. (NODE = 1000 is a
        // multiple of 4 and t0 is a multiple of 4, so groups never straddle.)
        int jm = 0;
        if (t0 < NODE) {
            int lim = NODE - t0; if (lim > valid) lim = valid;
            jm = lim >> 2;
        }
        const float4* mp0 = (const float4*)(mrow0 + t0);
        const float4* mp1 = (const float4*)(mrow1 + t0);

#define INNER(TAIL)                                                           \
        _Pragma("unroll")                                                     \
        for (int j4 = 0; j4 < KT / 4; ++j4) {                                 \
            float4 a  = (j4 < jm) ? mp0[j4] : z4;                             \
            float4 bm = (j4 < jm) ? mp1[j4] : z4;                             \
            _Pragma("unroll")                                                 \
            for (int jj = 0; jj < 4; ++jj) {                                  \
                int j = j4 * 4 + jj;                                          \
                float s0 = (jj == 0) ? a.x : (jj == 1) ? a.y                  \
                         : (jj == 2) ? a.z : a.w;                             \
                float s1 = (jj == 0) ? bm.x : (jj == 1) ? bm.y                \
                         : (jj == 2) ? bm.z : bm.w;                           \
                _Pragma("unroll")                                             \
                for (int e = 0; e < DH; e += 4) {                             \
                    float4 k4 = *(const float4*)&ks[j][h * DH + e];           \
                    s0 += q0[e]*k4.x + q0[e+1]*k4.y + q0[e+2]*k4.z + q0[e+3]*k4.w; \
                    s1 += q1r[e]*k4.x + q1r[e+1]*k4.y + q1r[e+2]*k4.z + q1r[e+3]*k4.w; \
                }                                                             \
                float p0 = __expf(s0), p1 = __expf(s1);                       \
                if (TAIL && j >= valid) { p0 = 0.f; p1 = 0.f; }               \
                l0 += p0; l1 += p1;                                           \
                _Pragma("unroll")                                             \
                for (int e = 0; e < DH; e += 4) {                             \
                    float4 v4 = *(const float4*)&vs[j][h * DH + e];           \
                    acc0[e+0] += p0*v4.x; acc0[e+1] += p0*v4.y;               \
                    acc0[e+2] += p0*v4.z; acc0[e+3] += p0*v4.w;               \
                    acc1[e+0] += p1*v4.x; acc1[e+1] += p1*v4.y;               \
                    acc1[e+2] += p1*v4.z; acc1[e+3] += p1*v4.w;               \
                }                                                             \
            }                                                                 \
        }
        if (valid == KT) { INNER(false) } else { INNER(true) }
#undef INNER
    }
    if (active) {
        long cb = ((long)(b * RTILES + tile) * SCH + c);
        // pacc: [cb][row32][h][16] -- dense 64B records, full-line wave stores
        long rec0 = ((cb * TROWS + rr * 2) * NH + h) * 16;
        long rec1 = rec0 + (long)NH * 16;
        #pragma unroll
        for (int i = 0; i < 4; ++i) {
            *(float4*)&pacc[rec0 + 4*i] =
                make_float4(acc0[4*i], acc0[4*i+1], acc0[4*i+2], acc0[4*i+3]);
            *(float4*)&pacc[rec1 + 4*i] =
                make_float4(acc1[4*i], acc1[4*i+1], acc1[4*i+2], acc1[4*i+3]);
        }
        // pl: [cb][h][row32] -- contiguous per (cb,h)
        long plrec = (cb * NH + h) * TROWS + rr * 2;
        *(float2*)&pl[plrec] = make_float2(l0, l1);
    }
}

// ---------------- merge key-split partials -> OC (plain sums) ---------------
__global__ __launch_bounds__(256) void attn_merge_kernel(
    const float* __restrict__ pacc, const float* __restrict__ pl,
    float* __restrict__ OC)
{
    int t = threadIdx.x;          // t = rt*8 + h
    int b = blockIdx.x, tile = blockIdx.y;
    int rt = t >> 3, h = t & 7;
    int row = tile * TROWS + rt;
    if (row >= POMO) return;
    long cb0 = (long)(b * RTILES + tile) * SCH;
    const long cs_acc = (long)TROWS * NH * 16;   // 4096 floats per chunk
    long abase = cb0 * cs_acc + ((long)rt * NH + h) * 16;
    const long cs_pl = (long)NH * TROWS;         // 256 floats per chunk
    long lbase = cb0 * cs_pl + (long)h * TROWS + rt;

    float L = 0.f;
    float o[16];
    #pragma unroll
    for (int i = 0; i < 16; ++i) o[i] = 0.f;
    #pragma unroll
    for (int c = 0; c < SCH; ++c) {
        L += pl[lbase + c * cs_pl];
        #pragma unroll
        for (int i4 = 0; i4 < 4; ++i4) {
            float4 a = *(const float4*)&pacc[abase + c * cs_acc + 4 * i4];
            o[4*i4+0] += a.x; o[4*i4+1] += a.y;
            o[4*i4+2] += a.z; o[4*i4+3] += a.w;
        }
    }
    float inv = 1.0f / L;
    float* op = OC + ((long)b * POMO + row) * EMB + h * DH;
    #pragma unroll
    for (int i4 = 0; i4 < 4; ++i4)
        *(float4*)&op[4*i4] = make_float4(o[4*i4]*inv, o[4*i4+1]*inv,
                                          o[4*i4+2]*inv, o[4*i4+3]*inv);
}

// ---------------- multi-head combine: mh = oc @ Wc.T ------------------------
__global__ __launch_bounds__(256) void combine_kernel(
    const float* __restrict__ OC, const float* __restrict__ W5,
    float* __restrict__ MH)
{
    __shared__ float xs[32][EMB];
    int t = threadIdx.x;
    long r0 = (long)blockIdx.x * 32;            // over 8000
    const float4* s4 = (const float4*)(OC + r0 * EMB);
    float4* xp = (float4*)&xs[0][0];
    for (int i = t; i < 32 * EMB / 4; i += 256) xp[i] = s4[i];
    __syncthreads();
    int o = t & 127;
    int rbase = (t >> 7) * 16;
    const float* W = W5 + 4 * EMB * EMB + o * EMB;
    float acc[16];
    #pragma unroll
    for (int r = 0; r < 16; ++r) acc[r] = 0.f;
    for (int e = 0; e < EMB; e += 4) {
        float4 w4 = *(const float4*)&W[e];
        #pragma unroll
        for (int r = 0; r < 16; ++r) {
            float4 x4 = *(const float4*)&xs[rbase + r][e];
            acc[r] += x4.x * w4.x + x4.y * w4.y + x4.z * w4.z + x4.w * w4.w;
        }
    }
    #pragma unroll
    for (int r = 0; r < 16; ++r) MH[(r0 + rbase + r) * EMB + o] = acc[r];
}

// ---------------- logits: 10*tanh((mh @ nodes.T)/sqrt(128)) + mask ----------
// 128x128 tile, K=128 in 32-wide slices, 8x8 register tile per thread:
// 16 MACs per b128 -> VALU-bound (~13 us floor). Bs groups padded to 12
// floats (48B): 16 read addrs span all banks 2-way = conflict-free.
__global__ __launch_bounds__(256, 2) void logits_kernel(
    const float* __restrict__ MH, const float* __restrict__ nodes,
    const float* __restrict__ mask, float* __restrict__ out)
{
    __shared__ float As[32][128];   // [e][n] 16 KB
    __shared__ float Bs[32][192];   // [e][16 groups * 12] 24 KB
    int t = threadIdx.x;
    int b = blockIdx.x;
    int n0 = blockIdx.y * 128;      // pomo rows
    int m0 = blockIdx.z * 128;      // node cols
    int ci = t & 15, ri = t >> 4;

    float acc[8][8];
    #pragma unroll
    for (int i = 0; i < 8; ++i)
        #pragma unroll
        for (int j = 0; j < 8; ++j) acc[i][j] = 0.f;

    int ln = t & 127;
    int eh = (t >> 7) * 16;
    int arow = n0 + ln; if (arow >= POMO) arow = POMO - 1;   // clamp reads
    const float* Arow = MH + ((long)b * POMO + arow) * EMB;
    const float* Brow = nodes + ((long)b * NKEY + m0 + ln) * EMB;  // m0+127<=1023<NKEY
    int bcol = (ln >> 3) * 12 + (ln & 7);

    for (int e0 = 0; e0 < EMB; e0 += 32) {
        if (e0) __syncthreads();
        #pragma unroll
        for (int u = 0; u < 4; ++u) {
            int e = eh + u * 4;
            float4 a4 = *(const float4*)&Arow[e0 + e];
            float4 b4 = *(const float4*)&Brow[e0 + e];
            As[e + 0][ln] = a4.x; As[e + 1][ln] = a4.y;
            As[e + 2][ln] = a4.z; As[e + 3][ln] = a4.w;
            Bs[e + 0][bcol] = b4.x; Bs[e + 1][bcol] = b4.y;
            Bs[e + 2][bcol] = b4.z; Bs[e + 3][bcol] = b4.w;
        }
        __syncthreads();
        #pragma unroll
        for (int e = 0; e < 32; ++e) {
            float4 a0 = *(const float4*)&As[e][ri * 8];
            float4 a1 = *(const float4*)&As[e][ri * 8 + 4];
            float4 b0 = *(const float4*)&Bs[e][ci * 12];
            float4 b1 = *(const float4*)&Bs[e][ci * 12 + 4];
            float av[8] = {a0.x, a0.y, a0.z, a0.w, a1.x, a1.y, a1.z, a1.w};
            float bv[8] = {b0.x, b0.y, b0.z, b0.w, b1.x, b1.y, b1.z, b1.w};
            #pragma unroll
            for (int i = 0; i < 8; ++i)
                #pragma unroll
                for (int j = 0; j < 8; ++j)
                    acc[i][j] += av[i] * bv[j];
        }
    }
    const float inv = 0.08838834764831845f;  // 1/sqrt(128)
    bool mfull = (m0 + 127 < NODE);
    int m = m0 + ci * 8;
    #pragma unroll
    for (int i = 0; i < 8; ++i) {
        int n = n0 + ri * 8 + i;
        if (n >= POMO) continue;
        long rbase = ((long)b * POMO + n) * NODE;
        if (mfull) {
            #pragma unroll
            for (int j4 = 0; j4 < 2; ++j4) {
                float4 mk = *(const float4*)&mask[rbase + m + j4 * 4];
                float4 r;
                r.x = tanh10(acc[i][j4*4+0] * inv) + mk.x;
                r.y = tanh10(acc[i][j4*4+1] * inv) + mk.y;
                r.z = tanh10(acc[i][j4*4+2] * inv) + mk.z;
                r.w = tanh10(acc[i][j4*4+3] * inv) + mk.w;
                *(float4*)&out[rbase + m + j4 * 4] = r;
            }
        } else {
            #pragma unroll
            for (int j = 0; j < 8; ++j) {
                int mm = m + j;
                if (mm < NODE)
                    out[rbase + mm] = tanh10(acc[i][j] * inv) + mask[rbase + mm];
            }
        }
    }
}

// ---------------- in-place row softmax over 1000 (shfl reduce) --------------
__global__ __launch_bounds__(256) void softmax_kernel(float* __restrict__ out)
{
    __shared__ float wred[8];
    int t = threadIdx.x;
    int w = t >> 6;
    float* p = out + (long)blockIdx.x * NODE;
    bool act = t < 250;
    float4 x = act ? *(const float4*)&p[t * 4]
                   : make_float4(-1e30f, -1e30f, -1e30f, -1e30f);
    float mx = fmaxf(fmaxf(x.x, x.y), fmaxf(x.z, x.w));
    #pragma unroll
    for (int s = 32; s >= 1; s >>= 1) mx = fmaxf(mx, __shfl_xor(mx, s));
    if ((t & 63) == 0) wred[w] = mx;
    __syncthreads();
    float M = fmaxf(fmaxf(wred[0], wred[1]), fmaxf(wred[2], wred[3]));
    float4 e;
    e.x = __expf(x.x - M); e.y = __expf(x.y - M);
    e.z = __expf(x.z - M); e.w = __expf(x.w - M);
    float sm = e.x + e.y + e.z + e.w;
    #pragma unroll
    for (int s = 32; s >= 1; s >>= 1) sm += __shfl_xor(sm, s);
    if ((t & 63) == 0) wred[4 + w] = sm;
    __syncthreads();
    float inv = 1.0f / (wred[4] + wred[5] + wred[6] + wred[7]);
    if (act) {
        float4 rr;
        rr.x = e.x * inv; rr.y = e.y * inv; rr.z = e.z * inv; rr.w = e.w * inv;
        *(float4*)&p[t * 4] = rr;
    }
}

extern "C" void kernel_launch(void* const* d_in, const int* in_sizes, int n_in,
                              void* d_out, int out_size, void* d_ws, size_t ws_size,
                              hipStream_t stream)
{
    const float* pref  = (const float*)d_in[0];
    const float* nodes = (const float*)d_in[1];
    const float* q1    = (const float*)d_in[2];
    const float* lastn = (const float*)d_in[3];
    const float* mask  = (const float*)d_in[4];
    const float* fc1_w = (const float*)d_in[5];
    const float* fc1_b = (const float*)d_in[6];
    const float* fc2_w = (const float*)d_in[7];
    const float* fc2_b = (const float*)d_in[8];
    const float* fc3_w = (const float*)d_in[9];
    const float* fc3_b = (const float*)d_in[10];
    const float* wqf   = (const float*)d_in[11];
    const float* wql   = (const float*)d_in[12];
    const float* wk    = (const float*)d_in[13];
    const float* wv    = (const float*)d_in[14];
    const float* wc    = (const float*)d_in[15];
    float* out = (float*)d_out;
    float* ws  = (float*)d_ws;

    float* W5 = ws;                                   // 5*16384 = 81920
    float* Kb = ws + 81920;                           // 8*1196*128
    float* Vb = Kb + (long)BB * NKEY * EMB;
    float* Qb = Vb + (long)BB * NKEY * EMB;           // 8*1000*128
    float* OC = Qb + (long)BB * POMO * EMB;
    float* MH = OC + (long)BB * POMO * EMB;
    float* gmid = MH + (long)BB * POMO * EMB;         // 16 floats, ~22.4 MB total

    float* pacc = out;                 // d_out (32 MB) as partial scratch
    float* pl   = out + PACC_FLOATS;   // fully overwritten by logits later

    hipLaunchKernelGGL(hyper_mid_kernel, dim3(1), dim3(256), 0, stream,
                       pref, fc1_w, fc1_b, fc2_w, fc2_b, fc3_w, fc3_b, gmid);
    hipLaunchKernelGGL(hyper_expand_kernel, dim3(40), dim3(256), 0, stream,
                       gmid, wqf, wql, wk, wv, wc, W5);
    hipLaunchKernelGGL(kv_proj_kernel, dim3(299), dim3(256), 0, stream, nodes, W5, Kb, Vb);
    hipLaunchKernelGGL(q_proj_kernel, dim3(250), dim3(256), 0, stream, q1, lastn, W5, Qb);
    hipLaunchKernelGGL(attn_split_kernel, dim3(8, RTILES, SCH), dim3(128), 0, stream,
                       Kb, Vb, Qb, mask, pacc, pl);
    hipLaunchKernelGGL(attn_merge_kernel, dim3(8, RTILES), dim3(256), 0, stream, pacc, pl, OC);
    hipLaunchKernelGGL(combine_kernel, dim3(250), dim3(256), 0, stream, OC, W5, MH);
    hipLaunchKernelGGL(logits_kernel, dim3(8, 8, 8), dim3(256), 0, stream, MH, nodes, mask, out);
    hipLaunchKernelGGL(softmax_kernel, dim3(8000), dim3(256), 0, stream, out);
}

// Round 9
// 537.511 us; speedup vs baseline: 4.2265x; 4.2265x over previous
//
#include <hip/hip_runtime.h>
#include <math.h>

#define EMB 128
#define NH 8
#define DH 16
#define HID 256
#define NODE 1000
#define PATCH 196
#define NKEY (NODE + PATCH)   // 1196
#define BB 8
#define POMO 1000
#define KT 16                  // attention key tile (proven staging/LDS shape)
#define SCH 6                  // key-split chunks
#define CKEYS 200              // keys per chunk (last = 196)
#define TILES16 16             // 1024/64 row tiles
#define TROWS 64               // rows per tile
#define ROWS 4                 // rows per thread

// partial buffers alias d_out (8M floats):
// pacc: [b][tile16][chunk][row64][h][16] = 8*16*6*64*8*16 = 6,291,456 floats
// pl  : [b][tile16][chunk][h][row64]     = 8*16*6*8*64    =   393,216 floats
#define PACC_FLOATS 6291456L

__device__ __forceinline__ float tanh10(float x) {
    float e = __expf(2.0f * x);
    return 10.0f * (1.0f - 2.0f / (e + 1.0f));
}

// ---------------- hypernet stage 1: pref -> mid[15] -------------------------
__global__ __launch_bounds__(256) void hyper_mid_kernel(
    const float* __restrict__ pref,
    const float* __restrict__ fc1_w, const float* __restrict__ fc1_b,
    const float* __restrict__ fc2_w, const float* __restrict__ fc2_b,
    const float* __restrict__ fc3_w, const float* __restrict__ fc3_b,
    float* __restrict__ gmid)
{
    __shared__ float h1[HID];
    __shared__ float h2[HID];
    int t = threadIdx.x;
    float p0 = pref[0], p1 = pref[1], p2 = pref[2];
    h1[t] = fc1_b[t] + p0 * fc1_w[t * 3 + 0] + p1 * fc1_w[t * 3 + 1] + p2 * fc1_w[t * 3 + 2];
    __syncthreads();
    {
        float s = fc2_b[t];
        const float4* w4 = (const float4*)(fc2_w + t * HID);
        const float4* h4 = (const float4*)h1;
        for (int j = 0; j < HID / 4; ++j) {
            float4 w = w4[j], x = h4[j];
            s += x.x * w.x + x.y * w.y + x.z * w.z + x.w * w.w;
        }
        h2[t] = s;
    }
    __syncthreads();
    if (t < 15) {
        float s = fc3_b[t];
        const float4* w4 = (const float4*)(fc3_w + t * HID);
        const float4* h4 = (const float4*)h2;
        for (int j = 0; j < HID / 4; ++j) {
            float4 w = w4[j], x = h4[j];
            s += x.x * w.x + x.y * w.y + x.z * w.z + x.w * w.w;
        }
        gmid[t] = s;
    }
}

// ---------------- hypernet stage 2: mid -> 5 weight matrices ----------------
__global__ __launch_bounds__(256) void hyper_expand_kernel(
    const float* __restrict__ gmid,
    const float* __restrict__ wqf, const float* __restrict__ wql,
    const float* __restrict__ wk,  const float* __restrict__ wv,
    const float* __restrict__ wc,  float* __restrict__ W5)
{
    int id = blockIdx.x;                 // 40 blocks: 5 mats x 8 segments
    int mat = id >> 3;
    int x0 = (id & 7) * 2048 + threadIdx.x * 8;
    const float* w = (mat == 0) ? wqf : (mat == 1) ? wql : (mat == 2) ? wk : (mat == 3) ? wv : wc;
    float m0 = gmid[mat * 3 + 0], m1 = gmid[mat * 3 + 1], m2 = gmid[mat * 3 + 2];
    float* dst = W5 + mat * EMB * EMB;
    #pragma unroll
    for (int i = 0; i < 8; ++i) {
        int x = x0 + i;
        dst[x] = m0 * w[x * 3 + 0] + m1 * w[x * 3 + 1] + m2 * w[x * 3 + 2];
    }
}

// ---------------- K,V projection of encoded_nodes ---------------------------
__global__ __launch_bounds__(256) void kv_proj_kernel(
    const float* __restrict__ nodes, const float* __restrict__ W5,
    float* __restrict__ Kb, float* __restrict__ Vb)
{
    __shared__ float xs[32][EMB];
    int t = threadIdx.x;
    long r0 = (long)blockIdx.x * 32;            // over BB*NKEY = 9568 (299*32 exact)
    const float4* s4 = (const float4*)(nodes + r0 * EMB);
    float4* x4p = (float4*)&xs[0][0];
    for (int i = t; i < 32 * EMB / 4; i += 256) x4p[i] = s4[i];
    __syncthreads();
    int o = t;
    const float* W = (o < EMB) ? (W5 + 2 * EMB * EMB + o * EMB)
                               : (W5 + 3 * EMB * EMB + (o - EMB) * EMB);
    float acc[32];
    #pragma unroll
    for (int r = 0; r < 32; ++r) acc[r] = 0.f;
    for (int e = 0; e < EMB; e += 4) {
        float4 w4 = *(const float4*)&W[e];
        #pragma unroll
        for (int r = 0; r < 32; ++r) {
            float4 x4 = *(const float4*)&xs[r][e];
            acc[r] += x4.x * w4.x + x4.y * w4.y + x4.z * w4.z + x4.w * w4.w;
        }
    }
    float* dst = (o < EMB) ? (Kb + r0 * EMB + o) : (Vb + r0 * EMB + (o - EMB));
    #pragma unroll
    for (int r = 0; r < 32; ++r) dst[(long)r * EMB] = acc[r];
}

// ---------------- Q projection: q1@Wqf.T + last@Wql.T -----------------------
__global__ __launch_bounds__(256) void q_proj_kernel(
    const float* __restrict__ q1, const float* __restrict__ lastn,
    const float* __restrict__ W5, float* __restrict__ Qb)
{
    __shared__ float xa[32][EMB];
    __shared__ float xb[32][EMB];
    int t = threadIdx.x;
    long r0 = (long)blockIdx.x * 32;            // over 8000 (250*32 exact)
    const float4* a4 = (const float4*)(q1 + r0 * EMB);
    const float4* b4 = (const float4*)(lastn + r0 * EMB);
    float4* xap = (float4*)&xa[0][0];
    float4* xbp = (float4*)&xb[0][0];
    for (int i = t; i < 32 * EMB / 4; i += 256) { xap[i] = a4[i]; xbp[i] = b4[i]; }
    __syncthreads();
    int o = t & 127;
    int rbase = (t >> 7) * 16;
    const float* Wf = W5 + 0 * EMB * EMB + o * EMB;
    const float* Wl = W5 + 1 * EMB * EMB + o * EMB;
    float acc[16];
    #pragma unroll
    for (int r = 0; r < 16; ++r) acc[r] = 0.f;
    for (int e = 0; e < EMB; e += 4) {
        float4 wf = *(const float4*)&Wf[e];
        float4 wl = *(const float4*)&Wl[e];
        #pragma unroll
        for (int r = 0; r < 16; ++r) {
            float4 va = *(const float4*)&xa[rbase + r][e];
            float4 vb = *(const float4*)&xb[rbase + r][e];
            acc[r] += va.x * wf.x + va.y * wf.y + va.z * wf.z + va.w * wf.w
                    + vb.x * wl.x + vb.y * wl.y + vb.z * wl.z + vb.w * wl.w;
        }
    }
    #pragma unroll
    for (int r = 0; r < 16; ++r) Qb[(r0 + rbase + r) * EMB + o] = acc[r];
}

// ---------------- fused masked MHA, key-split, no-max-shift, R=4 ------------
// grid (8, 16, 6): x=b (XCD-aligned), y=64-row tile, z=key chunk.
// block 128: h = t>>4, rr = t&15; thread owns rows {4rr..4rr+3}. One K/V LDS
// read serves 4 rows -> LDS floor ~47 us. __launch_bounds__(128, 1): min
// waves/EU=1 so the allocator may grant up to 512 VGPR -- the r6/r8 spills
// came from the min-waves=2 hint clipping the grant to 128.
__global__ __launch_bounds__(128, 1) void attn_split_kernel(
    const float* __restrict__ Kb, const float* __restrict__ Vb,
    const float* __restrict__ Qb, const float* __restrict__ mask,
    float* __restrict__ pacc, float* __restrict__ pl)
{
    __shared__ float ks[KT][EMB];   // 8 KB
    __shared__ float vs[KT][EMB];   // 8 KB
    int t = threadIdx.x;
    int b = blockIdx.x, tile = blockIdx.y, c = blockIdx.z;
    int rr = t & 15, h = t >> 4;
    int row0 = tile * TROWS + rr * ROWS;
    bool active = (row0 < POMO);               // row0 % 4 == 0, so all-or-none
    int qrow0 = active ? row0 : (POMO - ROWS); // clamped; stores guarded
    int kstart = c * CKEYS;
    int kend = kstart + CKEYS; if (kend > NKEY) kend = NKEY;
    bool has_mask = (kstart < NODE);           // chunks 0..4 node keys, 5 patch

    float q[ROWS][DH], acc[ROWS][DH], l[ROWS];
    const float* mrow[ROWS];
    #pragma unroll
    for (int r = 0; r < ROWS; ++r) {
        const float4* qp = (const float4*)(Qb + ((long)b * POMO + qrow0 + r) * EMB + h * DH);
        #pragma unroll
        for (int i = 0; i < 4; ++i) {
            float4 v = qp[i];   // pre-scale by 1/sqrt(16): s = q.k + mask
            q[r][4*i+0] = v.x*0.25f; q[r][4*i+1] = v.y*0.25f;
            q[r][4*i+2] = v.z*0.25f; q[r][4*i+3] = v.w*0.25f;
        }
        #pragma unroll
        for (int i = 0; i < DH; ++i) acc[r][i] = 0.f;
        l[r] = 0.f;
        mrow[r] = mask + ((long)b * POMO + qrow0 + r) * NODE;
    }

    const float4* ksrc = (const float4*)(Kb + (long)b * NKEY * EMB);
    const float4* vsrc = (const float4*)(Vb + (long)b * NKEY * EMB);
    const int max4 = NKEY * (EMB / 4) - 1;
    const float4 z4 = make_float4(0.f, 0.f, 0.f, 0.f);

    for (int t0 = kstart; t0 < kend; t0 += KT) {
        int valid = kend - t0; if (valid > KT) valid = KT;   // 16, 8 or 4
        __syncthreads();
        {   // stage K,V tile via transient registers (L2-friendly), clamped
            float4* kd = (float4*)&ks[0][0];
            float4* vd = (float4*)&vs[0][0];
            int base4 = t0 * (EMB / 4);
            #pragma unroll
            for (int u = 0; u < 4; ++u) {
                int i = t + u * 128;
                int src = base4 + i; if (src > max4) src = max4;
                kd[i] = ksrc[src];
                vd[i] = vsrc[src];
            }
        }
        __syncthreads();

        int mv4 = valid >> 2;

#define TILE_COMPUTE(TAIL)                                                    \
        _Pragma("unroll")                                                     \
        for (int j4 = 0; j4 < KT / 4; ++j4) {                                 \
            float4 m4[ROWS];                                                  \
            if (has_mask) {                                                   \
                _Pragma("unroll")                                             \
                for (int r = 0; r < ROWS; ++r) {                              \
                    const float4* mp = (const float4*)(mrow[r] + t0);         \
                    m4[r] = (!TAIL || j4 < mv4) ? mp[j4] : z4;                \
                }                                                             \
            } else {                                                          \
                _Pragma("unroll")                                             \
                for (int r = 0; r < ROWS; ++r) m4[r] = z4;                    \
            }                                                                 \
            _Pragma("unroll")                                                 \
            for (int jj = 0; jj < 4; ++jj) {                                  \
                int j = j4 * 4 + jj;                                          \
                float4 k0 = *(const float4*)&ks[j][h * DH + 0];               \
                float4 k1 = *(const float4*)&ks[j][h * DH + 4];               \
                float4 k2 = *(const float4*)&ks[j][h * DH + 8];               \
                float4 k3 = *(const float4*)&ks[j][h * DH + 12];              \
                float p[ROWS];                                                \
                _Pragma("unroll")                                             \
                for (int r = 0; r < ROWS; ++r) {                              \
                    float s = (jj == 0) ? m4[r].x : (jj == 1) ? m4[r].y       \
                            : (jj == 2) ? m4[r].z : m4[r].w;                  \
                    s += q[r][0]*k0.x + q[r][1]*k0.y + q[r][2]*k0.z + q[r][3]*k0.w; \
                    s += q[r][4]*k1.x + q[r][5]*k1.y + q[r][6]*k1.z + q[r][7]*k1.w; \
                    s += q[r][8]*k2.x + q[r][9]*k2.y + q[r][10]*k2.z + q[r][11]*k2.w; \
                    s += q[r][12]*k3.x + q[r][13]*k3.y + q[r][14]*k3.z + q[r][15]*k3.w; \
                    float pv = __expf(s);                                     \
                    if (TAIL && j >= valid) pv = 0.f;                         \
                    p[r] = pv; l[r] += pv;                                    \
                }                                                             \
                float4 v0 = *(const float4*)&vs[j][h * DH + 0];               \
                float4 v1 = *(const float4*)&vs[j][h * DH + 4];               \
                float4 v2 = *(const float4*)&vs[j][h * DH + 8];               \
                float4 v3 = *(const float4*)&vs[j][h * DH + 12];              \
                _Pragma("unroll")                                             \
                for (int r = 0; r < ROWS; ++r) {                              \
                    acc[r][0] += p[r]*v0.x;  acc[r][1] += p[r]*v0.y;          \
                    acc[r][2] += p[r]*v0.z;  acc[r][3] += p[r]*v0.w;          \
                    acc[r][4] += p[r]*v1.x;  acc[r][5] += p[r]*v1.y;          \
                    acc[r][6] += p[r]*v1.z;  acc[r][7] += p[r]*v1.w;          \
                    acc[r][8] += p[r]*v2.x;  acc[r][9] += p[r]*v2.y;          \
                    acc[r][10] += p[r]*v2.z; acc[r][11] += p[r]*v2.w;         \
                    acc[r][12] += p[r]*v3.x; acc[r][13] += p[r]*v3.y;         \
                    acc[r][14] += p[r]*v3.z; acc[r][15] += p[r]*v3.w;         \
                }                                                             \
            }                                                                 \
        }
        if (valid == KT) { TILE_COMPUTE(false) } else { TILE_COMPUTE(true) }
#undef TILE_COMPUTE
    }
    if (active) {
        long cb = ((long)(b * TILES16 + tile) * SCH + c);
        // pacc: [cb][row64][h][16] -- dense 64B records, full-line wave stores
        #pragma unroll
        for (int r = 0; r < ROWS; ++r) {
            long rec = ((cb * TROWS + rr * ROWS + r) * NH + h) * 16;
            #pragma unroll
            for (int i = 0; i < 4; ++i)
                *(float4*)&pacc[rec + 4*i] =
                    make_float4(acc[r][4*i], acc[r][4*i+1], acc[r][4*i+2], acc[r][4*i+3]);
        }
        // pl: [cb][h][row64] -- one float4 per thread, contiguous per (cb,h)
        *(float4*)&pl[(cb * NH + h) * TROWS + rr * ROWS] =
            make_float4(l[0], l[1], l[2], l[3]);
    }
}

// ---------------- merge key-split partials -> OC (plain sums) ---------------
__global__ __launch_bounds__(512) void attn_merge_kernel(
    const float* __restrict__ pacc, const float* __restrict__ pl,
    float* __restrict__ OC)
{
    int t = threadIdx.x;          // t = rt*8 + h
    int b = blockIdx.x, tile = blockIdx.y;
    int rt = t >> 3, h = t & 7;
    int row = tile * TROWS + rt;
    if (row >= POMO) return;
    long cb0 = (long)(b * TILES16 + tile) * SCH;
    const long cs_acc = (long)TROWS * NH * 16;   // 8192 floats per chunk
    long abase = cb0 * cs_acc + ((long)rt * NH + h) * 16;
    const long cs_pl = (long)NH * TROWS;         // 512 floats per chunk
    long lbase = cb0 * cs_pl + (long)h * TROWS + rt;

    float L = 0.f;
    float o[16];
    #pragma unroll
    for (int i = 0; i < 16; ++i) o[i] = 0.f;
    #pragma unroll
    for (int c = 0; c < SCH; ++c) {
        L += pl[lbase + c * cs_pl];
        #pragma unroll
        for (int i4 = 0; i4 < 4; ++i4) {
            float4 a = *(const float4*)&pacc[abase + c * cs_acc + 4 * i4];
            o[4*i4+0] += a.x; o[4*i4+1] += a.y;
            o[4*i4+2] += a.z; o[4*i4+3] += a.w;
        }
    }
    float inv = 1.0f / L;
    float* op = OC + ((long)b * POMO + row) * EMB + h * DH;
    #pragma unroll
    for (int i4 = 0; i4 < 4; ++i4)
        *(float4*)&op[4*i4] = make_float4(o[4*i4]*inv, o[4*i4+1]*inv,
                                          o[4*i4+2]*inv, o[4*i4+3]*inv);
}

// ---------------- multi-head combine: mh = oc @ Wc.T ------------------------
__global__ __launch_bounds__(256) void combine_kernel(
    const float* __restrict__ OC, const float* __restrict__ W5,
    float* __restrict__ MH)
{
    __shared__ float xs[32][EMB];
    int t = threadIdx.x;
    long r0 = (long)blockIdx.x * 32;            // over 8000
    const float4* s4 = (const float4*)(OC + r0 * EMB);
    float4* xp = (float4*)&xs[0][0];
    for (int i = t; i < 32 * EMB / 4; i += 256) xp[i] = s4[i];
    __syncthreads();
    int o = t & 127;
    int rbase = (t >> 7) * 16;
    const float* W = W5 + 4 * EMB * EMB + o * EMB;
    float acc[16];
    #pragma unroll
    for (int r = 0; r < 16; ++r) acc[r] = 0.f;
    for (int e = 0; e < EMB; e += 4) {
        float4 w4 = *(const float4*)&W[e];
        #pragma unroll
        for (int r = 0; r < 16; ++r) {
            float4 x4 = *(const float4*)&xs[rbase + r][e];
            acc[r] += x4.x * w4.x + x4.y * w4.y + x4.z * w4.z + x4.w * w4.w;
        }
    }
    #pragma unroll
    for (int r = 0; r < 16; ++r) MH[(r0 + rbase + r) * EMB + o] = acc[r];
}

// ---------------- logits: 10*tanh((mh @ nodes.T)/sqrt(128)) + mask ----------
__global__ __launch_bounds__(256, 2) void logits_kernel(
    const float* __restrict__ MH, const float* __restrict__ nodes,
    const float* __restrict__ mask, float* __restrict__ out)
{
    __shared__ float As[32][128];   // [e][n] 16 KB
    __shared__ float Bs[32][192];   // [e][16 groups * 12] 24 KB
    int t = threadIdx.x;
    int b = blockIdx.x;
    int n0 = blockIdx.y * 128;      // pomo rows
    int m0 = blockIdx.z * 128;      // node cols
    int ci = t & 15, ri = t >> 4;

    float acc[8][8];
    #pragma unroll
    for (int i = 0; i < 8; ++i)
        #pragma unroll
        for (int j = 0; j < 8; ++j) acc[i][j] = 0.f;

    int ln = t & 127;
    int eh = (t >> 7) * 16;
    int arow = n0 + ln; if (arow >= POMO) arow = POMO - 1;   // clamp reads
    const float* Arow = MH + ((long)b * POMO + arow) * EMB;
    const float* Brow = nodes + ((long)b * NKEY + m0 + ln) * EMB;  // m0+127<NKEY
    int bcol = (ln >> 3) * 12 + (ln & 7);

    for (int e0 = 0; e0 < EMB; e0 += 32) {
        if (e0) __syncthreads();
        #pragma unroll
        for (int u = 0; u < 4; ++u) {
            int e = eh + u * 4;
            float4 a4 = *(const float4*)&Arow[e0 + e];
            float4 b4 = *(const float4*)&Brow[e0 + e];
            As[e + 0][ln] = a4.x; As[e + 1][ln] = a4.y;
            As[e + 2][ln] = a4.z; As[e + 3][ln] = a4.w;
            Bs[e + 0][bcol] = b4.x; Bs[e + 1][bcol] = b4.y;
            Bs[e + 2][bcol] = b4.z; Bs[e + 3][bcol] = b4.w;
        }
        __syncthreads();
        #pragma unroll
        for (int e = 0; e < 32; ++e) {
            float4 a0 = *(const float4*)&As[e][ri * 8];
            float4 a1 = *(const float4*)&As[e][ri * 8 + 4];
            float4 b0 = *(const float4*)&Bs[e][ci * 12];
            float4 b1 = *(const float4*)&Bs[e][ci * 12 + 4];
            float av[8] = {a0.x, a0.y, a0.z, a0.w, a1.x, a1.y, a1.z, a1.w};
            float bv[8] = {b0.x, b0.y, b0.z, b0.w, b1.x, b1.y, b1.z, b1.w};
            #pragma unroll
            for (int i = 0; i < 8; ++i)
                #pragma unroll
                for (int j = 0; j < 8; ++j)
                    acc[i][j] += av[i] * bv[j];
        }
    }
    const float inv = 0.08838834764831845f;  // 1/sqrt(128)
    bool mfull = (m0 + 127 < NODE);
    int m = m0 + ci * 8;
    #pragma unroll
    for (int i = 0; i < 8; ++i) {
        int n = n0 + ri * 8 + i;
        if (n >= POMO) continue;
        long rbase = ((long)b * POMO + n) * NODE;
        if (mfull) {
            #pragma unroll
            for (int j4 = 0; j4 < 2; ++j4) {
                float4 mk = *(const float4*)&mask[rbase + m + j4 * 4];
                float4 r;
                r.x = tanh10(acc[i][j4*4+0] * inv) + mk.x;
                r.y = tanh10(acc[i][j4*4+1] * inv) + mk.y;
                r.z = tanh10(acc[i][j4*4+2] * inv) + mk.z;
                r.w = tanh10(acc[i][j4*4+3] * inv) + mk.w;
                *(float4*)&out[rbase + m + j4 * 4] = r;
            }
        } else {
            #pragma unroll
            for (int j = 0; j < 8; ++j) {
                int mm = m + j;
                if (mm < NODE)
                    out[rbase + mm] = tanh10(acc[i][j] * inv) + mask[rbase + mm];
            }
        }
    }
}

// ---------------- in-place row softmax over 1000 (shfl reduce) --------------
__global__ __launch_bounds__(256) void softmax_kernel(float* __restrict__ out)
{
    __shared__ float wred[8];
    int t = threadIdx.x;
    int w = t >> 6;
    float* p = out + (long)blockIdx.x * NODE;
    bool act = t < 250;
    float4 x = act ? *(const float4*)&p[t * 4]
                   : make_float4(-1e30f, -1e30f, -1e30f, -1e30f);
    float mx = fmaxf(fmaxf(x.x, x.y), fmaxf(x.z, x.w));
    #pragma unroll
    for (int s = 32; s >= 1; s >>= 1) mx = fmaxf(mx, __shfl_xor(mx, s));
    if ((t & 63) == 0) wred[w] = mx;
    __syncthreads();
    float M = fmaxf(fmaxf(wred[0], wred[1]), fmaxf(wred[2], wred[3]));
    float4 e;
    e.x = __expf(x.x - M); e.y = __expf(x.y - M);
    e.z = __expf(x.z - M); e.w = __expf(x.w - M);
    float sm = e.x + e.y + e.z + e.w;
    #pragma unroll
    for (int s = 32; s >= 1; s >>= 1) sm += __shfl_xor(sm, s);
    if ((t & 63) == 0) wred[4 + w] = sm;
    __syncthreads();
    float inv = 1.0f / (wred[4] + wred[5] + wred[6] + wred[7]);
    if (act) {
        float4 rr;
        rr.x = e.x * inv; rr.y = e.y * inv; rr.z = e.z * inv; rr.w = e.w * inv;
        *(float4*)&p[t * 4] = rr;
    }
}

extern "C" void kernel_launch(void* const* d_in, const int* in_sizes, int n_in,
                              void* d_out, int out_size, void* d_ws, size_t ws_size,
                              hipStream_t stream)
{
    const float* pref  = (const float*)d_in[0];
    const float* nodes = (const float*)d_in[1];
    const float* q1    = (const float*)d_in[2];
    const float* lastn = (const float*)d_in[3];
    const float* mask  = (const float*)d_in[4];
    const float* fc1_w = (const float*)d_in[5];
    const float* fc1_b = (const float*)d_in[6];
    const float* fc2_w = (const float*)d_in[7];
    const float* fc2_b = (const float*)d_in[8];
    const float* fc3_w = (const float*)d_in[9];
    const float* fc3_b = (const float*)d_in[10];
    const float* wqf   = (const float*)d_in[11];
    const float* wql   = (const float*)d_in[12];
    const float* wk    = (const float*)d_in[13];
    const float* wv    = (const float*)d_in[14];
    const float* wc    = (const float*)d_in[15];
    float* out = (float*)d_out;
    float* ws  = (float*)d_ws;

    float* W5 = ws;                                   // 5*16384 = 81920
    float* Kb = ws + 81920;                           // 8*1196*128
    float* Vb = Kb + (long)BB * NKEY * EMB;
    float* Qb = Vb + (long)BB * NKEY * EMB;           // 8*1000*128
    float* OC = Qb + (long)BB * POMO * EMB;
    float* MH = OC + (long)BB * POMO * EMB;
    float* gmid = MH + (long)BB * POMO * EMB;         // 16 floats, ~22.4 MB total

    float* pacc = out;                 // d_out (32 MB) as partial scratch
    float* pl   = out + PACC_FLOATS;   // fully overwritten by logits later

    hipLaunchKernelGGL(hyper_mid_kernel, dim3(1), dim3(256), 0, stream,
                       pref, fc1_w, fc1_b, fc2_w, fc2_b, fc3_w, fc3_b, gmid);
    hipLaunchKernelGGL(hyper_expand_kernel, dim3(40), dim3(256), 0, stream,
                       gmid, wqf, wql, wk, wv, wc, W5);
    hipLaunchKernelGGL(kv_proj_kernel, dim3(299), dim3(256), 0, stream, nodes, W5, Kb, Vb);
    hipLaunchKernelGGL(q_proj_kernel, dim3(250), dim3(256), 0, stream, q1, lastn, W5, Qb);
    hipLaunchKernelGGL(attn_split_kernel, dim3(8, TILES16, SCH), dim3(128), 0, stream,
                       Kb, Vb, Qb, mask, pacc, pl);
    hipLaunchKernelGGL(attn_merge_kernel, dim3(8, TILES16), dim3(512), 0, stream, pacc, pl, OC);
    hipLaunchKernelGGL(combine_kernel, dim3(250), dim3(256), 0, stream, OC, W5, MH);
    hipLaunchKernelGGL(logits_kernel, dim3(8, 8, 8), dim3(256), 0, stream, MH, nodes, mask, out);
    hipLaunchKernelGGL(softmax_kernel, dim3(8000), dim3(256), 0, stream, out);
}

// Round 10
// 433.607 us; speedup vs baseline: 5.2393x; 1.2396x over previous
//
#include <hip/hip_runtime.h>
#include <math.h>

#define EMB 128
#define NH 8
#define DH 16
#define HID 256
#define NODE 1000
#define PATCH 196
#define NKEY (NODE + PATCH)   // 1196
#define BB 8
#define POMO 1000
#define KT 16                  // attention key tile
#define SCH 5                  // key-split chunks
#define CKEYS 240              // keys per chunk (last = 236)
#define RTILES 32              // 32-row tiles
#define TROWS 32

// partial buffers alias d_out (8M floats):
// pacc: [b][tile][chunk][row32][h][16] = 8*32*5*32*8*16 = 5,242,880 floats
// pl  : [b][tile][chunk][h][row32]     = 8*32*5*8*32    =   327,680 floats
#define PACC_FLOATS 5242880L

__device__ __forceinline__ float tanh10(float x) {
    float e = __expf(2.0f * x);
    return 10.0f * (1.0f - 2.0f / (e + 1.0f));
}

// ---------------- hypernet stage 1: pref -> mid[15] -------------------------
__global__ __launch_bounds__(256) void hyper_mid_kernel(
    const float* __restrict__ pref,
    const float* __restrict__ fc1_w, const float* __restrict__ fc1_b,
    const float* __restrict__ fc2_w, const float* __restrict__ fc2_b,
    const float* __restrict__ fc3_w, const float* __restrict__ fc3_b,
    float* __restrict__ gmid)
{
    __shared__ float h1[HID];
    __shared__ float h2[HID];
    int t = threadIdx.x;
    float p0 = pref[0], p1 = pref[1], p2 = pref[2];
    h1[t] = fc1_b[t] + p0 * fc1_w[t * 3 + 0] + p1 * fc1_w[t * 3 + 1] + p2 * fc1_w[t * 3 + 2];
    __syncthreads();
    {
        float s = fc2_b[t];
        const float4* w4 = (const float4*)(fc2_w + t * HID);
        const float4* h4 = (const float4*)h1;
        for (int j = 0; j < HID / 4; ++j) {
            float4 w = w4[j], x = h4[j];
            s += x.x * w.x + x.y * w.y + x.z * w.z + x.w * w.w;
        }
        h2[t] = s;
    }
    __syncthreads();
    if (t < 15) {
        float s = fc3_b[t];
        const float4* w4 = (const float4*)(fc3_w + t * HID);
        const float4* h4 = (const float4*)h2;
        for (int j = 0; j < HID / 4; ++j) {
            float4 w = w4[j], x = h4[j];
            s += x.x * w.x + x.y * w.y + x.z * w.z + x.w * w.w;
        }
        gmid[t] = s;
    }
}

// ---------------- hypernet stage 2: mid -> 5 weight matrices ----------------
__global__ __launch_bounds__(256) void hyper_expand_kernel(
    const float* __restrict__ gmid,
    const float* __restrict__ wqf, const float* __restrict__ wql,
    const float* __restrict__ wk,  const float* __restrict__ wv,
    const float* __restrict__ wc,  float* __restrict__ W5)
{
    int id = blockIdx.x;                 // 40 blocks: 5 mats x 8 segments
    int mat = id >> 3;
    int x0 = (id & 7) * 2048 + threadIdx.x * 8;
    const float* w = (mat == 0) ? wqf : (mat == 1) ? wql : (mat == 2) ? wk : (mat == 3) ? wv : wc;
    float m0 = gmid[mat * 3 + 0], m1 = gmid[mat * 3 + 1], m2 = gmid[mat * 3 + 2];
    float* dst = W5 + mat * EMB * EMB;
    #pragma unroll
    for (int i = 0; i < 8; ++i) {
        int x = x0 + i;
        dst[x] = m0 * w[x * 3 + 0] + m1 * w[x * 3 + 1] + m2 * w[x * 3 + 2];
    }
}

// ---------------- K,V projection of encoded_nodes ---------------------------
__global__ __launch_bounds__(256) void kv_proj_kernel(
    const float* __restrict__ nodes, const float* __restrict__ W5,
    float* __restrict__ Kb, float* __restrict__ Vb)
{
    __shared__ float xs[32][EMB];
    int t = threadIdx.x;
    long r0 = (long)blockIdx.x * 32;            // over BB*NKEY = 9568 (299*32 exact)
    const float4* s4 = (const float4*)(nodes + r0 * EMB);
    float4* x4p = (float4*)&xs[0][0];
    for (int i = t; i < 32 * EMB / 4; i += 256) x4p[i] = s4[i];
    __syncthreads();
    int o = t;
    const float* W = (o < EMB) ? (W5 + 2 * EMB * EMB + o * EMB)
                               : (W5 + 3 * EMB * EMB + (o - EMB) * EMB);
    float acc[32];
    #pragma unroll
    for (int r = 0; r < 32; ++r) acc[r] = 0.f;
    for (int e = 0; e < EMB; e += 4) {
        float4 w4 = *(const float4*)&W[e];
        #pragma unroll
        for (int r = 0; r < 32; ++r) {
            float4 x4 = *(const float4*)&xs[r][e];
            acc[r] += x4.x * w4.x + x4.y * w4.y + x4.z * w4.z + x4.w * w4.w;
        }
    }
    float* dst = (o < EMB) ? (Kb + r0 * EMB + o) : (Vb + r0 * EMB + (o - EMB));
    #pragma unroll
    for (int r = 0; r < 32; ++r) dst[(long)r * EMB] = acc[r];
}

// ---------------- Q projection: q1@Wqf.T + last@Wql.T -----------------------
__global__ __launch_bounds__(256) void q_proj_kernel(
    const float* __restrict__ q1, const float* __restrict__ lastn,
    const float* __restrict__ W5, float* __restrict__ Qb)
{
    __shared__ float xa[32][EMB];
    __shared__ float xb[32][EMB];
    int t = threadIdx.x;
    long r0 = (long)blockIdx.x * 32;            // over 8000 (250*32 exact)
    const float4* a4 = (const float4*)(q1 + r0 * EMB);
    const float4* b4 = (const float4*)(lastn + r0 * EMB);
    float4* xap = (float4*)&xa[0][0];
    float4* xbp = (float4*)&xb[0][0];
    for (int i = t; i < 32 * EMB / 4; i += 256) { xap[i] = a4[i]; xbp[i] = b4[i]; }
    __syncthreads();
    int o = t & 127;
    int rbase = (t >> 7) * 16;
    const float* Wf = W5 + 0 * EMB * EMB + o * EMB;
    const float* Wl = W5 + 1 * EMB * EMB + o * EMB;
    float acc[16];
    #pragma unroll
    for (int r = 0; r < 16; ++r) acc[r] = 0.f;
    for (int e = 0; e < EMB; e += 4) {
        float4 wf = *(const float4*)&Wf[e];
        float4 wl = *(const float4*)&Wl[e];
        #pragma unroll
        for (int r = 0; r < 16; ++r) {
            float4 va = *(const float4*)&xa[rbase + r][e];
            float4 vb = *(const float4*)&xb[rbase + r][e];
            acc[r] += va.x * wf.x + va.y * wf.y + va.z * wf.z + va.w * wf.w
                    + vb.x * wl.x + vb.y * wl.y + vb.z * wl.z + vb.w * wl.w;
        }
    }
    #pragma unroll
    for (int r = 0; r < 16; ++r) Qb[(r0 + rbase + r) * EMB + o] = acc[r];
}

// ---------------- fused masked MHA, key-split, no-max-shift, R=2, dbuf ------
// grid (8, 32, 5): x=b (XCD-aligned), y=32-row tile, z=key chunk. 1280 blocks
// = exactly 5 blocks/CU (LDS-limited), one residency round.
// block 128: h = t>>4, rr = t&15; thread owns rows {2rr, 2rr+1} (the proven
// no-spill envelope). Double-buffered LDS + issue-early staging: one barrier
// per tile, global latency hidden under compute. Mask via per-tile jm window.
__global__ __launch_bounds__(128, 1) void attn_split_kernel(
    const float* __restrict__ Kb, const float* __restrict__ Vb,
    const float* __restrict__ Qb, const float* __restrict__ mask,
    float* __restrict__ pacc, float* __restrict__ pl)
{
    __shared__ float ks[2][KT][EMB];   // 16 KB
    __shared__ float vs[2][KT][EMB];   // 16 KB
    int t = threadIdx.x;
    int b = blockIdx.x, tile = blockIdx.y, c = blockIdx.z;
    int rr = t & 15, h = t >> 4;
    int row0 = tile * TROWS + rr * 2;
    bool active = (row0 < POMO);
    int qrow = active ? row0 : (POMO - 2);     // clamped; stores guarded
    int kstart = c * CKEYS;
    int kend = kstart + CKEYS; if (kend > NKEY) kend = NKEY;

    float q0[DH], q1r[DH];
    {
        const float4* qp0 = (const float4*)(Qb + ((long)b * POMO + qrow) * EMB + h * DH);
        const float4* qp1 = (const float4*)(Qb + ((long)b * POMO + qrow + 1) * EMB + h * DH);
        #pragma unroll
        for (int i = 0; i < 4; ++i) {
            float4 v = qp0[i];   // pre-scale by 1/sqrt(16): s = q.k + mask
            q0[4*i+0] = v.x*0.25f; q0[4*i+1] = v.y*0.25f;
            q0[4*i+2] = v.z*0.25f; q0[4*i+3] = v.w*0.25f;
            float4 w = qp1[i];
            q1r[4*i+0] = w.x*0.25f; q1r[4*i+1] = w.y*0.25f;
            q1r[4*i+2] = w.z*0.25f; q1r[4*i+3] = w.w*0.25f;
        }
    }
    float acc0[DH], acc1[DH];
    #pragma unroll
    for (int i = 0; i < DH; ++i) { acc0[i] = 0.f; acc1[i] = 0.f; }
    float l0 = 0.f, l1 = 0.f;

    const float4* ksrc = (const float4*)(Kb + (long)b * NKEY * EMB);
    const float4* vsrc = (const float4*)(Vb + (long)b * NKEY * EMB);
    const int max4 = NKEY * (EMB / 4) - 1;
    const float* mrow0 = mask + ((long)b * POMO + qrow) * NODE;
    const float* mrow1 = mrow0 + NODE;
    const float4 z4 = make_float4(0.f, 0.f, 0.f, 0.f);

    // prologue: issue loads for first tile
    float4 kr[4], vr[4];
    {
        int base4 = kstart * (EMB / 4);
        #pragma unroll
        for (int u = 0; u < 4; ++u) {
            int src = base4 + t + u * 128; if (src > max4) src = max4;
            kr[u] = ksrc[src]; vr[u] = vsrc[src];
        }
    }

    int pbuf = 0;
    for (int t0 = kstart; t0 < kend; t0 += KT) {
        int valid = kend - t0; if (valid > KT) valid = KT;   // 16 or 12
        {   // write staged regs to LDS buf, then issue next tile's loads
            float4* kd = (float4*)&ks[pbuf][0][0];
            float4* vd = (float4*)&vs[pbuf][0][0];
            #pragma unroll
            for (int u = 0; u < 4; ++u) {
                kd[t + u * 128] = kr[u];
                vd[t + u * 128] = vr[u];
            }
            int nt0 = t0 + KT;
            if (nt0 < kend) {
                int nb4 = nt0 * (EMB / 4);
                #pragma unroll
                for (int u = 0; u < 4; ++u) {
                    int src = nb4 + t + u * 128; if (src > max4) src = max4;
                    kr[u] = ksrc[src]; vr[u] = vsrc[src];
                }
            }
        }
        __syncthreads();

        // float4 key-groups carrying mask: j4 < jm (NODE, t0, valid all
        // multiples of 4 -> groups never straddle the node/patch boundary)
        int jm = 0;
        if (t0 < NODE) {
            int lim = NODE - t0; if (lim > valid) lim = valid;
            jm = lim >> 2;
        }
        const float4* mp0 = (const float4*)(mrow0 + t0);
        const float4* mp1 = (const float4*)(mrow1 + t0);
        const float (*ksb)[EMB] = ks[pbuf];
        const float (*vsb)[EMB] = vs[pbuf];

#define INNER(TAIL)                                                           \
        _Pragma("unroll")                                                     \
        for (int j4 = 0; j4 < KT / 4; ++j4) {                                 \
            float4 a  = (j4 < jm) ? mp0[j4] : z4;                             \
            float4 bm = (j4 < jm) ? mp1[j4] : z4;                             \
            _Pragma("unroll")                                                 \
            for (int jj = 0; jj < 4; ++jj) {                                  \
                int j = j4 * 4 + jj;                                          \
                float s0 = (jj == 0) ? a.x : (jj == 1) ? a.y                  \
                         : (jj == 2) ? a.z : a.w;                             \
                float s1 = (jj == 0) ? bm.x : (jj == 1) ? bm.y                \
                         : (jj == 2) ? bm.z : bm.w;                           \
                _Pragma("unroll")                                             \
                for (int e = 0; e < DH; e += 4) {                             \
                    float4 k4 = *(const float4*)&ksb[j][h * DH + e];          \
                    s0 += q0[e]*k4.x + q0[e+1]*k4.y + q0[e+2]*k4.z + q0[e+3]*k4.w; \
                    s1 += q1r[e]*k4.x + q1r[e+1]*k4.y + q1r[e+2]*k4.z + q1r[e+3]*k4.w; \
                }                                                             \
                float p0 = __expf(s0), p1 = __expf(s1);                       \
                if (TAIL && j >= valid) { p0 = 0.f; p1 = 0.f; }               \
                l0 += p0; l1 += p1;                                           \
                _Pragma("unroll")                                             \
                for (int e = 0; e < DH; e += 4) {                             \
                    float4 v4 = *(const float4*)&vsb[j][h * DH + e];          \
                    acc0[e+0] += p0*v4.x; acc0[e+1] += p0*v4.y;               \
                    acc0[e+2] += p0*v4.z; acc0[e+3] += p0*v4.w;               \
                    acc1[e+0] += p1*v4.x; acc1[e+1] += p1*v4.y;               \
                    acc1[e+2] += p1*v4.z; acc1[e+3] += p1*v4.w;               \
                }                                                             \
            }                                                                 \
        }
        if (valid == KT) { INNER(false) } else { INNER(true) }
#undef INNER
        pbuf ^= 1;
    }
    if (active) {
        long cb = ((long)(b * RTILES + tile) * SCH + c);
        // pacc: [cb][row32][h][16] -- dense 64B records, full-line wave stores
        long rec0 = ((cb * TROWS + rr * 2) * NH + h) * 16;
        long rec1 = rec0 + (long)NH * 16;
        #pragma unroll
        for (int i = 0; i < 4; ++i) {
            *(float4*)&pacc[rec0 + 4*i] =
                make_float4(acc0[4*i], acc0[4*i+1], acc0[4*i+2], acc0[4*i+3]);
            *(float4*)&pacc[rec1 + 4*i] =
                make_float4(acc1[4*i], acc1[4*i+1], acc1[4*i+2], acc1[4*i+3]);
        }
        // pl: [cb][h][row32] -- contiguous per (cb,h)
        long plrec = (cb * NH + h) * TROWS + rr * 2;
        *(float2*)&pl[plrec] = make_float2(l0, l1);
    }
}

// ---------------- merge key-split partials -> OC (plain sums) ---------------
__global__ __launch_bounds__(256) void attn_merge_kernel(
    const float* __restrict__ pacc, const float* __restrict__ pl,
    float* __restrict__ OC)
{
    int t = threadIdx.x;          // t = rt*8 + h
    int b = blockIdx.x, tile = blockIdx.y;
    int rt = t >> 3, h = t & 7;
    int row = tile * TROWS + rt;
    if (row >= POMO) return;
    long cb0 = (long)(b * RTILES + tile) * SCH;
    const long cs_acc = (long)TROWS * NH * 16;   // 4096 floats per chunk
    long abase = cb0 * cs_acc + ((long)rt * NH + h) * 16;
    const long cs_pl = (long)NH * TROWS;         // 256 floats per chunk
    long lbase = cb0 * cs_pl + (long)h * TROWS + rt;

    float L = 0.f;
    float o[16];
    #pragma unroll
    for (int i = 0; i < 16; ++i) o[i] = 0.f;
    #pragma unroll
    for (int c = 0; c < SCH; ++c) {
        L += pl[lbase + c * cs_pl];
        #pragma unroll
        for (int i4 = 0; i4 < 4; ++i4) {
            float4 a = *(const float4*)&pacc[abase + c * cs_acc + 4 * i4];
            o[4*i4+0] += a.x; o[4*i4+1] += a.y;
            o[4*i4+2] += a.z; o[4*i4+3] += a.w;
        }
    }
    float inv = 1.0f / L;
    float* op = OC + ((long)b * POMO + row) * EMB + h * DH;
    #pragma unroll
    for (int i4 = 0; i4 < 4; ++i4)
        *(float4*)&op[4*i4] = make_float4(o[4*i4]*inv, o[4*i4+1]*inv,
                                          o[4*i4+2]*inv, o[4*i4+3]*inv);
}

// ---------------- multi-head combine: mh = oc @ Wc.T ------------------------
__global__ __launch_bounds__(256) void combine_kernel(
    const float* __restrict__ OC, const float* __restrict__ W5,
    float* __restrict__ MH)
{
    __shared__ float xs[32][EMB];
    int t = threadIdx.x;
    long r0 = (long)blockIdx.x * 32;            // over 8000
    const float4* s4 = (const float4*)(OC + r0 * EMB);
    float4* xp = (float4*)&xs[0][0];
    for (int i = t; i < 32 * EMB / 4; i += 256) xp[i] = s4[i];
    __syncthreads();
    int o = t & 127;
    int rbase = (t >> 7) * 16;
    const float* W = W5 + 4 * EMB * EMB + o * EMB;
    float acc[16];
    #pragma unroll
    for (int r = 0; r < 16; ++r) acc[r] = 0.f;
    for (int e = 0; e < EMB; e += 4) {
        float4 w4 = *(const float4*)&W[e];
        #pragma unroll
        for (int r = 0; r < 16; ++r) {
            float4 x4 = *(const float4*)&xs[rbase + r][e];
            acc[r] += x4.x * w4.x + x4.y * w4.y + x4.z * w4.z + x4.w * w4.w;
        }
    }
    #pragma unroll
    for (int r = 0; r < 16; ++r) MH[(r0 + rbase + r) * EMB + o] = acc[r];
}

// ---------------- logits: 10*tanh((mh @ nodes.T)/sqrt(128)) + mask ----------
__global__ __launch_bounds__(256, 2) void logits_kernel(
    const float* __restrict__ MH, const float* __restrict__ nodes,
    const float* __restrict__ mask, float* __restrict__ out)
{
    __shared__ float As[32][128];   // [e][n] 16 KB
    __shared__ float Bs[32][192];   // [e][16 groups * 12] 24 KB
    int t = threadIdx.x;
    int b = blockIdx.x;
    int n0 = blockIdx.y * 128;      // pomo rows
    int m0 = blockIdx.z * 128;      // node cols
    int ci = t & 15, ri = t >> 4;

    float acc[8][8];
    #pragma unroll
    for (int i = 0; i < 8; ++i)
        #pragma unroll
        for (int j = 0; j < 8; ++j) acc[i][j] = 0.f;

    int ln = t & 127;
    int eh = (t >> 7) * 16;
    int arow = n0 + ln; if (arow >= POMO) arow = POMO - 1;   // clamp reads
    const float* Arow = MH + ((long)b * POMO + arow) * EMB;
    const float* Brow = nodes + ((long)b * NKEY + m0 + ln) * EMB;  // m0+127<NKEY
    int bcol = (ln >> 3) * 12 + (ln & 7);

    for (int e0 = 0; e0 < EMB; e0 += 32) {
        if (e0) __syncthreads();
        #pragma unroll
        for (int u = 0; u < 4; ++u) {
            int e = eh + u * 4;
            float4 a4 = *(const float4*)&Arow[e0 + e];
            float4 b4 = *(const float4*)&Brow[e0 + e];
            As[e + 0][ln] = a4.x; As[e + 1][ln] = a4.y;
            As[e + 2][ln] = a4.z; As[e + 3][ln] = a4.w;
            Bs[e + 0][bcol] = b4.x; Bs[e + 1][bcol] = b4.y;
            Bs[e + 2][bcol] = b4.z; Bs[e + 3][bcol] = b4.w;
        }
        __syncthreads();
        #pragma unroll
        for (int e = 0; e < 32; ++e) {
            float4 a0 = *(const float4*)&As[e][ri * 8];
            float4 a1 = *(const float4*)&As[e][ri * 8 + 4];
            float4 b0 = *(const float4*)&Bs[e][ci * 12];
            float4 b1 = *(const float4*)&Bs[e][ci * 12 + 4];
            float av[8] = {a0.x, a0.y, a0.z, a0.w, a1.x, a1.y, a1.z, a1.w};
            float bv[8] = {b0.x, b0.y, b0.z, b0.w, b1.x, b1.y, b1.z, b1.w};
            #pragma unroll
            for (int i = 0; i < 8; ++i)
                #pragma unroll
                for (int j = 0; j < 8; ++j)
                    acc[i][j] += av[i] * bv[j];
        }
    }
    const float inv = 0.08838834764831845f;  // 1/sqrt(128)
    bool mfull = (m0 + 127 < NODE);
    int m = m0 + ci * 8;
    #pragma unroll
    for (int i = 0; i < 8; ++i) {
        int n = n0 + ri * 8 + i;
        if (n >= POMO) continue;
        long rbase = ((long)b * POMO + n) * NODE;
        if (mfull) {
            #pragma unroll
            for (int j4 = 0; j4 < 2; ++j4) {
                float4 mk = *(const float4*)&mask[rbase + m + j4 * 4];
                float4 r;
                r.x = tanh10(acc[i][j4*4+0] * inv) + mk.x;
                r.y = tanh10(acc[i][j4*4+1] * inv) + mk.y;
                r.z = tanh10(acc[i][j4*4+2] * inv) + mk.z;
                r.w = tanh10(acc[i][j4*4+3] * inv) + mk.w;
                *(float4*)&out[rbase + m + j4 * 4] = r;
            }
        } else {
            #pragma unroll
            for (int j = 0; j < 8; ++j) {
                int mm = m + j;
                if (mm < NODE)
                    out[rbase + mm] = tanh10(acc[i][j] * inv) + mask[rbase + mm];
            }
        }
    }
}

// ---------------- in-place row softmax over 1000 (shfl reduce) --------------
__global__ __launch_bounds__(256) void softmax_kernel(float* __restrict__ out)
{
    __shared__ float wred[8];
    int t = threadIdx.x;
    int w = t >> 6;
    float* p = out + (long)blockIdx.x * NODE;
    bool act = t < 250;
    float4 x = act ? *(const float4*)&p[t * 4]
                   : make_float4(-1e30f, -1e30f, -1e30f, -1e30f);
    float mx = fmaxf(fmaxf(x.x, x.y), fmaxf(x.z, x.w));
    #pragma unroll
    for (int s = 32; s >= 1; s >>= 1) mx = fmaxf(mx, __shfl_xor(mx, s));
    if ((t & 63) == 0) wred[w] = mx;
    __syncthreads();
    float M = fmaxf(fmaxf(wred[0], wred[1]), fmaxf(wred[2], wred[3]));
    float4 e;
    e.x = __expf(x.x - M); e.y = __expf(x.y - M);
    e.z = __expf(x.z - M); e.w = __expf(x.w - M);
    float sm = e.x + e.y + e.z + e.w;
    #pragma unroll
    for (int s = 32; s >= 1; s >>= 1) sm += __shfl_xor(sm, s);
    if ((t & 63) == 0) wred[4 + w] = sm;
    __syncthreads();
    float inv = 1.0f / (wred[4] + wred[5] + wred[6] + wred[7]);
    if (act) {
        float4 rr;
        rr.x = e.x * inv; rr.y = e.y * inv; rr.z = e.z * inv; rr.w = e.w * inv;
        *(float4*)&p[t * 4] = rr;
    }
}

extern "C" void kernel_launch(void* const* d_in, const int* in_sizes, int n_in,
                              void* d_out, int out_size, void* d_ws, size_t ws_size,
                              hipStream_t stream)
{
    const float* pref  = (const float*)d_in[0];
    const float* nodes = (const float*)d_in[1];
    const float* q1    = (const float*)d_in[2];
    const float* lastn = (const float*)d_in[3];
    const float* mask  = (const float*)d_in[4];
    const float* fc1_w = (const float*)d_in[5];
    const float* fc1_b = (const float*)d_in[6];
    const float* fc2_w = (const float*)d_in[7];
    const float* fc2_b = (const float*)d_in[8];
    const float* fc3_w = (const float*)d_in[9];
    const float* fc3_b = (const float*)d_in[10];
    const float* wqf   = (const float*)d_in[11];
    const float* wql   = (const float*)d_in[12];
    const float* wk    = (const float*)d_in[13];
    const float* wv    = (const float*)d_in[14];
    const float* wc    = (const float*)d_in[15];
    float* out = (float*)d_out;
    float* ws  = (float*)d_ws;

    float* W5 = ws;                                   // 5*16384 = 81920
    float* Kb = ws + 81920;                           // 8*1196*128
    float* Vb = Kb + (long)BB * NKEY * EMB;
    float* Qb = Vb + (long)BB * NKEY * EMB;           // 8*1000*128
    float* OC = Qb + (long)BB * POMO * EMB;
    float* MH = OC + (long)BB * POMO * EMB;
    float* gmid = MH + (long)BB * POMO * EMB;         // 16 floats, ~22.4 MB total

    float* pacc = out;                 // d_out (32 MB) as partial scratch
    float* pl   = out + PACC_FLOATS;   // fully overwritten by logits later

    hipLaunchKernelGGL(hyper_mid_kernel, dim3(1), dim3(256), 0, stream,
                       pref, fc1_w, fc1_b, fc2_w, fc2_b, fc3_w, fc3_b, gmid);
    hipLaunchKernelGGL(hyper_expand_kernel, dim3(40), dim3(256), 0, stream,
                       gmid, wqf, wql, wk, wv, wc, W5);
    hipLaunchKernelGGL(kv_proj_kernel, dim3(299), dim3(256), 0, stream, nodes, W5, Kb, Vb);
    hipLaunchKernelGGL(q_proj_kernel, dim3(250), dim3(256), 0, stream, q1, lastn, W5, Qb);
    hipLaunchKernelGGL(attn_split_kernel, dim3(8, RTILES, SCH), dim3(128), 0, stream,
                       Kb, Vb, Qb, mask, pacc, pl);
    hipLaunchKernelGGL(attn_merge_kernel, dim3(8, RTILES), dim3(256), 0, stream, pacc, pl, OC);
    hipLaunchKernelGGL(combine_kernel, dim3(250), dim3(256), 0, stream, OC, W5, MH);
    hipLaunchKernelGGL(logits_kernel, dim3(8, 8, 8), dim3(256), 0, stream, MH, nodes, mask, out);
    hipLaunchKernelGGL(softmax_kernel, dim3(8000), dim3(256), 0, stream, out);
}

// Round 11
// 315.031 us; speedup vs baseline: 7.2113x; 1.3764x over previous
//
#include <hip/hip_runtime.h>
#include <math.h>

#define EMB 128
#define NH 8
#define DH 16
#define HID 256
#define NODE 1000
#define PATCH 196
#define NKEY (NODE + PATCH)   // 1196
#define BB 8
#define POMO 1000
#define KT 16                  // attention key tile
#define SCH 6                  // key-split chunks
#define CKEYS 200              // keys per chunk (last = 196)
#define RTILES 32              // 32-row tiles
#define TROWS 32

// partial buffers alias d_out (8M floats):
// pacc: [b][tile][chunk][row32][h][16] = 8*32*6*32*8*16 = 6,291,456 floats
// pl  : [b][tile][chunk][h][row32]     = 8*32*6*8*32    =   393,216 floats
#define PACC_FLOATS 6291456L

__device__ __forceinline__ float tanh10(float x) {
    float e = __expf(2.0f * x);
    return 10.0f * (1.0f - 2.0f / (e + 1.0f));
}

// ---------------- hypernet stage 1: pref -> mid[15] -------------------------
__global__ __launch_bounds__(256) void hyper_mid_kernel(
    const float* __restrict__ pref,
    const float* __restrict__ fc1_w, const float* __restrict__ fc1_b,
    const float* __restrict__ fc2_w, const float* __restrict__ fc2_b,
    const float* __restrict__ fc3_w, const float* __restrict__ fc3_b,
    float* __restrict__ gmid)
{
    __shared__ float h1[HID];
    __shared__ float h2[HID];
    int t = threadIdx.x;
    float p0 = pref[0], p1 = pref[1], p2 = pref[2];
    h1[t] = fc1_b[t] + p0 * fc1_w[t * 3 + 0] + p1 * fc1_w[t * 3 + 1] + p2 * fc1_w[t * 3 + 2];
    __syncthreads();
    {
        float s = fc2_b[t];
        const float4* w4 = (const float4*)(fc2_w + t * HID);
        const float4* h4 = (const float4*)h1;
        for (int j = 0; j < HID / 4; ++j) {
            float4 w = w4[j], x = h4[j];
            s += x.x * w.x + x.y * w.y + x.z * w.z + x.w * w.w;
        }
        h2[t] = s;
    }
    __syncthreads();
    if (t < 15) {
        float s = fc3_b[t];
        const float4* w4 = (const float4*)(fc3_w + t * HID);
        const float4* h4 = (const float4*)h2;
        for (int j = 0; j < HID / 4; ++j) {
            float4 w = w4[j], x = h4[j];
            s += x.x * w.x + x.y * w.y + x.z * w.z + x.w * w.w;
        }
        gmid[t] = s;
    }
}

// ---------------- hypernet stage 2: mid -> 5 weight matrices ----------------
__global__ __launch_bounds__(256) void hyper_expand_kernel(
    const float* __restrict__ gmid,
    const float* __restrict__ wqf, const float* __restrict__ wql,
    const float* __restrict__ wk,  const float* __restrict__ wv,
    const float* __restrict__ wc,  float* __restrict__ W5)
{
    int id = blockIdx.x;                 // 40 blocks: 5 mats x 8 segments
    int mat = id >> 3;
    int x0 = (id & 7) * 2048 + threadIdx.x * 8;
    const float* w = (mat == 0) ? wqf : (mat == 1) ? wql : (mat == 2) ? wk : (mat == 3) ? wv : wc;
    float m0 = gmid[mat * 3 + 0], m1 = gmid[mat * 3 + 1], m2 = gmid[mat * 3 + 2];
    float* dst = W5 + mat * EMB * EMB;
    #pragma unroll
    for (int i = 0; i < 8; ++i) {
        int x = x0 + i;
        dst[x] = m0 * w[x * 3 + 0] + m1 * w[x * 3 + 1] + m2 * w[x * 3 + 2];
    }
}

// ---------------- K,V projection of encoded_nodes ---------------------------
__global__ __launch_bounds__(256) void kv_proj_kernel(
    const float* __restrict__ nodes, const float* __restrict__ W5,
    float* __restrict__ Kb, float* __restrict__ Vb)
{
    __shared__ float xs[32][EMB];
    int t = threadIdx.x;
    long r0 = (long)blockIdx.x * 32;            // over BB*NKEY = 9568 (299*32 exact)
    const float4* s4 = (const float4*)(nodes + r0 * EMB);
    float4* x4p = (float4*)&xs[0][0];
    for (int i = t; i < 32 * EMB / 4; i += 256) x4p[i] = s4[i];
    __syncthreads();
    int o = t;
    const float* W = (o < EMB) ? (W5 + 2 * EMB * EMB + o * EMB)
                               : (W5 + 3 * EMB * EMB + (o - EMB) * EMB);
    float acc[32];
    #pragma unroll
    for (int r = 0; r < 32; ++r) acc[r] = 0.f;
    for (int e = 0; e < EMB; e += 4) {
        float4 w4 = *(const float4*)&W[e];
        #pragma unroll
        for (int r = 0; r < 32; ++r) {
            float4 x4 = *(const float4*)&xs[r][e];
            acc[r] += x4.x * w4.x + x4.y * w4.y + x4.z * w4.z + x4.w * w4.w;
        }
    }
    float* dst = (o < EMB) ? (Kb + r0 * EMB + o) : (Vb + r0 * EMB + (o - EMB));
    #pragma unroll
    for (int r = 0; r < 32; ++r) dst[(long)r * EMB] = acc[r];
}

// ---------------- Q projection: q1@Wqf.T + last@Wql.T -----------------------
__global__ __launch_bounds__(256) void q_proj_kernel(
    const float* __restrict__ q1, const float* __restrict__ lastn,
    const float* __restrict__ W5, float* __restrict__ Qb)
{
    __shared__ float xa[32][EMB];
    __shared__ float xb[32][EMB];
    int t = threadIdx.x;
    long r0 = (long)blockIdx.x * 32;            // over 8000 (250*32 exact)
    const float4* a4 = (const float4*)(q1 + r0 * EMB);
    const float4* b4 = (const float4*)(lastn + r0 * EMB);
    float4* xap = (float4*)&xa[0][0];
    float4* xbp = (float4*)&xb[0][0];
    for (int i = t; i < 32 * EMB / 4; i += 256) { xap[i] = a4[i]; xbp[i] = b4[i]; }
    __syncthreads();
    int o = t & 127;
    int rbase = (t >> 7) * 16;
    const float* Wf = W5 + 0 * EMB * EMB + o * EMB;
    const float* Wl = W5 + 1 * EMB * EMB + o * EMB;
    float acc[16];
    #pragma unroll
    for (int r = 0; r < 16; ++r) acc[r] = 0.f;
    for (int e = 0; e < EMB; e += 4) {
        float4 wf = *(const float4*)&Wf[e];
        float4 wl = *(const float4*)&Wl[e];
        #pragma unroll
        for (int r = 0; r < 16; ++r) {
            float4 va = *(const float4*)&xa[rbase + r][e];
            float4 vb = *(const float4*)&xb[rbase + r][e];
            acc[r] += va.x * wf.x + va.y * wf.y + va.z * wf.z + va.w * wf.w
                    + vb.x * wl.x + vb.y * wl.y + vb.z * wl.z + vb.w * wl.w;
        }
    }
    #pragma unroll
    for (int r = 0; r < 16; ++r) Qb[(r0 + rbase + r) * EMB + o] = acc[r];
}

// ---------------- fused masked MHA, key-split, NO-max-shift flash -----------
// (r5's exact kernel: the verified 128-VGPR/no-spill operating point)
// grid (8, 32, 6): x=b (XCD-aligned), y=32-row tile, z=key chunk.
// block 128: h = t>>4, rr = t&15; thread owns rows {2rr, 2rr+1}.
__global__ __launch_bounds__(128, 2) void attn_split_kernel(
    const float* __restrict__ Kb, const float* __restrict__ Vb,
    const float* __restrict__ Qb, const float* __restrict__ mask,
    float* __restrict__ pacc, float* __restrict__ pl)
{
    __shared__ float ks[KT][EMB];
    __shared__ float vs[KT][EMB];
    int t = threadIdx.x;
    int b = blockIdx.x;
    int tile = blockIdx.y;
    int c = blockIdx.z;
    int rr = t & 15;
    int h = t >> 4;
    int row0 = tile * TROWS + rr * 2;
    bool active = (row0 < POMO);
    int qrow = active ? row0 : (POMO - 2);     // clamped; stores guarded
    int kstart = c * CKEYS;
    int kend = kstart + CKEYS; if (kend > NKEY) kend = NKEY;
    bool has_mask = (kstart < NODE);           // chunks 0..4 node keys, 5 pure patch

    float q0[DH], q1r[DH];
    {
        const float4* qp0 = (const float4*)(Qb + ((long)b * POMO + qrow) * EMB + h * DH);
        const float4* qp1 = (const float4*)(Qb + ((long)b * POMO + qrow + 1) * EMB + h * DH);
        #pragma unroll
        for (int i = 0; i < 4; ++i) {
            float4 v = qp0[i];   // pre-scale by 1/sqrt(16): s = q.k + mask
            q0[4*i+0] = v.x*0.25f; q0[4*i+1] = v.y*0.25f;
            q0[4*i+2] = v.z*0.25f; q0[4*i+3] = v.w*0.25f;
            float4 w = qp1[i];
            q1r[4*i+0] = w.x*0.25f; q1r[4*i+1] = w.y*0.25f;
            q1r[4*i+2] = w.z*0.25f; q1r[4*i+3] = w.w*0.25f;
        }
    }
    float acc0[DH], acc1[DH];
    #pragma unroll
    for (int i = 0; i < DH; ++i) { acc0[i] = 0.f; acc1[i] = 0.f; }
    float l0 = 0.f, l1 = 0.f;

    const float4* ksrc = (const float4*)(Kb + (long)b * NKEY * EMB);
    const float4* vsrc = (const float4*)(Vb + (long)b * NKEY * EMB);
    const int max4 = NKEY * (EMB / 4) - 1;
    const float* mrow0 = mask + ((long)b * POMO + qrow) * NODE;
    const float* mrow1 = mrow0 + NODE;

    for (int t0 = kstart; t0 < kend; t0 += KT) {
        int valid = kend - t0; if (valid > KT) valid = KT;
        __syncthreads();
        {   // stage K,V tile via registers (L2-friendly), clamped source
            float4* kd = (float4*)&ks[0][0];
            float4* vd = (float4*)&vs[0][0];
            int base4 = t0 * (EMB / 4);
            #pragma unroll
            for (int u = 0; u < 4; ++u) {
                int i = t + u * 128;
                int src = base4 + i; if (src > max4) src = max4;
                kd[i] = ksrc[src];
                vd[i] = vsrc[src];
            }
        }
        __syncthreads();

        // mask values (whole float4s by construction: valid is 16, 8 or 4)
        float mk0[KT], mk1[KT];
        if (has_mask) {
            const float4* mp0 = (const float4*)(mrow0 + t0);
            const float4* mp1 = (const float4*)(mrow1 + t0);
            int mv4 = valid >> 2;
            #pragma unroll
            for (int j4 = 0; j4 < KT / 4; ++j4) {
                float4 a = (j4 < mv4) ? mp0[j4] : make_float4(0,0,0,0);
                float4 bm = (j4 < mv4) ? mp1[j4] : make_float4(0,0,0,0);
                mk0[4*j4+0]=a.x;  mk0[4*j4+1]=a.y;  mk0[4*j4+2]=a.z;  mk0[4*j4+3]=a.w;
                mk1[4*j4+0]=bm.x; mk1[4*j4+1]=bm.y; mk1[4*j4+2]=bm.z; mk1[4*j4+3]=bm.w;
            }
        } else {
            #pragma unroll
            for (int j = 0; j < KT; ++j) { mk0[j] = 0.f; mk1[j] = 0.f; }
        }

#define INNER(TAIL)                                                          \
        _Pragma("unroll")                                                    \
        for (int j = 0; j < KT; ++j) {                                       \
            float s0 = mk0[j], s1 = mk1[j];                                  \
            _Pragma("unroll")                                                \
            for (int e = 0; e < DH; e += 4) {                                \
                float4 k4 = *(const float4*)&ks[j][h * DH + e];              \
                s0 += q0[e]*k4.x + q0[e+1]*k4.y + q0[e+2]*k4.z + q0[e+3]*k4.w; \
                s1 += q1r[e]*k4.x + q1r[e+1]*k4.y + q1r[e+2]*k4.z + q1r[e+3]*k4.w; \
            }                                                                \
            float p0 = __expf(s0), p1 = __expf(s1);                          \
            if (TAIL && j >= valid) { p0 = 0.f; p1 = 0.f; }                  \
            l0 += p0; l1 += p1;                                              \
            _Pragma("unroll")                                                \
            for (int e = 0; e < DH; e += 4) {                                \
                float4 v4 = *(const float4*)&vs[j][h * DH + e];              \
                acc0[e+0] += p0*v4.x; acc0[e+1] += p0*v4.y;                  \
                acc0[e+2] += p0*v4.z; acc0[e+3] += p0*v4.w;                  \
                acc1[e+0] += p1*v4.x; acc1[e+1] += p1*v4.y;                  \
                acc1[e+2] += p1*v4.z; acc1[e+3] += p1*v4.w;                  \
            }                                                                \
        }
        if (valid == KT) { INNER(false) } else { INNER(true) }
#undef INNER
    }
    if (active) {
        long cb = ((long)(b * RTILES + tile) * SCH + c);
        // pacc: [cb][row32][h][16] -- dense 64B records, full-line wave stores
        long rec0 = ((cb * TROWS + rr * 2) * NH + h) * 16;
        long rec1 = rec0 + (long)NH * 16;
        #pragma unroll
        for (int i = 0; i < 4; ++i) {
            *(float4*)&pacc[rec0 + 4*i] =
                make_float4(acc0[4*i], acc0[4*i+1], acc0[4*i+2], acc0[4*i+3]);
            *(float4*)&pacc[rec1 + 4*i] =
                make_float4(acc1[4*i], acc1[4*i+1], acc1[4*i+2], acc1[4*i+3]);
        }
        // pl: [cb][h][row32] -- contiguous per (cb,h)
        long plrec = (cb * NH + h) * TROWS + rr * 2;
        *(float2*)&pl[plrec] = make_float2(l0, l1);
    }
}

// ---------------- merge key-split partials -> OC (plain sums) ---------------
__global__ __launch_bounds__(256) void attn_merge_kernel(
    const float* __restrict__ pacc, const float* __restrict__ pl,
    float* __restrict__ OC)
{
    int t = threadIdx.x;          // t = rt*8 + h
    int b = blockIdx.x, tile = blockIdx.y;
    int rt = t >> 3, h = t & 7;
    int row = tile * TROWS + rt;
    if (row >= POMO) return;
    long cb0 = (long)(b * RTILES + tile) * SCH;
    const long cs_acc = (long)TROWS * NH * 16;   // 4096 floats per chunk
    long abase = cb0 * cs_acc + ((long)rt * NH + h) * 16;
    const long cs_pl = (long)NH * TROWS;         // 256 floats per chunk
    long lbase = cb0 * cs_pl + (long)h * TROWS + rt;

    float L = 0.f;
    float o[16];
    #pragma unroll
    for (int i = 0; i < 16; ++i) o[i] = 0.f;
    #pragma unroll
    for (int c = 0; c < SCH; ++c) {
        L += pl[lbase + c * cs_pl];
        #pragma unroll
        for (int i4 = 0; i4 < 4; ++i4) {
            float4 a = *(const float4*)&pacc[abase + c * cs_acc + 4 * i4];
            o[4*i4+0] += a.x; o[4*i4+1] += a.y;
            o[4*i4+2] += a.z; o[4*i4+3] += a.w;
        }
    }
    float inv = 1.0f / L;
    float* op = OC + ((long)b * POMO + row) * EMB + h * DH;
    #pragma unroll
    for (int i4 = 0; i4 < 4; ++i4)
        *(float4*)&op[4*i4] = make_float4(o[4*i4]*inv, o[4*i4+1]*inv,
                                          o[4*i4+2]*inv, o[4*i4+3]*inv);
}

// ---------------- multi-head combine: mh = oc @ Wc.T ------------------------
__global__ __launch_bounds__(256) void combine_kernel(
    const float* __restrict__ OC, const float* __restrict__ W5,
    float* __restrict__ MH)
{
    __shared__ float xs[32][EMB];
    int t = threadIdx.x;
    long r0 = (long)blockIdx.x * 32;            // over 8000
    const float4* s4 = (const float4*)(OC + r0 * EMB);
    float4* xp = (float4*)&xs[0][0];
    for (int i = t; i < 32 * EMB / 4; i += 256) xp[i] = s4[i];
    __syncthreads();
    int o = t & 127;
    int rbase = (t >> 7) * 16;
    const float* W = W5 + 4 * EMB * EMB + o * EMB;
    float acc[16];
    #pragma unroll
    for (int r = 0; r < 16; ++r) acc[r] = 0.f;
    for (int e = 0; e < EMB; e += 4) {
        float4 w4 = *(const float4*)&W[e];
        #pragma unroll
        for (int r = 0; r < 16; ++r) {
            float4 x4 = *(const float4*)&xs[rbase + r][e];
            acc[r] += x4.x * w4.x + x4.y * w4.y + x4.z * w4.z + x4.w * w4.w;
        }
    }
    #pragma unroll
    for (int r = 0; r < 16; ++r) MH[(r0 + rbase + r) * EMB + o] = acc[r];
}

// ---------------- logits: 10*tanh((mh @ nodes.T)/sqrt(128)) + mask ----------
// 128x128 tile, K=128 in 32-wide slices, 8x8 register tile per thread.
__global__ __launch_bounds__(256, 2) void logits_kernel(
    const float* __restrict__ MH, const float* __restrict__ nodes,
    const float* __restrict__ mask, float* __restrict__ out)
{
    __shared__ float As[32][128];   // [e][n] 16 KB
    __shared__ float Bs[32][192];   // [e][16 groups * 12] 24 KB
    int t = threadIdx.x;
    int b = blockIdx.x;
    int n0 = blockIdx.y * 128;      // pomo rows
    int m0 = blockIdx.z * 128;      // node cols
    int ci = t & 15, ri = t >> 4;

    float acc[8][8];
    #pragma unroll
    for (int i = 0; i < 8; ++i)
        #pragma unroll
        for (int j = 0; j < 8; ++j) acc[i][j] = 0.f;

    int ln = t & 127;
    int eh = (t >> 7) * 16;
    int arow = n0 + ln; if (arow >= POMO) arow = POMO - 1;   // clamp reads
    const float* Arow = MH + ((long)b * POMO + arow) * EMB;
    const float* Brow = nodes + ((long)b * NKEY + m0 + ln) * EMB;  // m0+127<NKEY
    int bcol = (ln >> 3) * 12 + (ln & 7);

    for (int e0 = 0; e0 < EMB; e0 += 32) {
        if (e0) __syncthreads();
        #pragma unroll
        for (int u = 0; u < 4; ++u) {
            int e = eh + u * 4;
            float4 a4 = *(const float4*)&Arow[e0 + e];
            float4 b4 = *(const float4*)&Brow[e0 + e];
            As[e + 0][ln] = a4.x; As[e + 1][ln] = a4.y;
            As[e + 2][ln] = a4.z; As[e + 3][ln] = a4.w;
            Bs[e + 0][bcol] = b4.x; Bs[e + 1][bcol] = b4.y;
            Bs[e + 2][bcol] = b4.z; Bs[e + 3][bcol] = b4.w;
        }
        __syncthreads();
        #pragma unroll
        for (int e = 0; e < 32; ++e) {
            float4 a0 = *(const float4*)&As[e][ri * 8];
            float4 a1 = *(const float4*)&As[e][ri * 8 + 4];
            float4 b0 = *(const float4*)&Bs[e][ci * 12];
            float4 b1 = *(const float4*)&Bs[e][ci * 12 + 4];
            float av[8] = {a0.x, a0.y, a0.z, a0.w, a1.x, a1.y, a1.z, a1.w};
            float bv[8] = {b0.x, b0.y, b0.z, b0.w, b1.x, b1.y, b1.z, b1.w};
            #pragma unroll
            for (int i = 0; i < 8; ++i)
                #pragma unroll
                for (int j = 0; j < 8; ++j)
                    acc[i][j] += av[i] * bv[j];
        }
    }
    const float inv = 0.08838834764831845f;  // 1/sqrt(128)
    bool mfull = (m0 + 127 < NODE);
    int m = m0 + ci * 8;
    #pragma unroll
    for (int i = 0; i < 8; ++i) {
        int n = n0 + ri * 8 + i;
        if (n >= POMO) continue;
        long rbase = ((long)b * POMO + n) * NODE;
        if (mfull) {
            #pragma unroll
            for (int j4 = 0; j4 < 2; ++j4) {
                float4 mk = *(const float4*)&mask[rbase + m + j4 * 4];
                float4 r;
                r.x = tanh10(acc[i][j4*4+0] * inv) + mk.x;
                r.y = tanh10(acc[i][j4*4+1] * inv) + mk.y;
                r.z = tanh10(acc[i][j4*4+2] * inv) + mk.z;
                r.w = tanh10(acc[i][j4*4+3] * inv) + mk.w;
                *(float4*)&out[rbase + m + j4 * 4] = r;
            }
        } else {
            #pragma unroll
            for (int j = 0; j < 8; ++j) {
                int mm = m + j;
                if (mm < NODE)
                    out[rbase + mm] = tanh10(acc[i][j] * inv) + mask[rbase + mm];
            }
        }
    }
}

// ---------------- in-place row softmax over 1000 (shfl reduce) --------------
__global__ __launch_bounds__(256) void softmax_kernel(float* __restrict__ out)
{
    __shared__ float wred[8];
    int t = threadIdx.x;
    int w = t >> 6;
    float* p = out + (long)blockIdx.x * NODE;
    bool act = t < 250;
    float4 x = act ? *(const float4*)&p[t * 4]
                   : make_float4(-1e30f, -1e30f, -1e30f, -1e30f);
    float mx = fmaxf(fmaxf(x.x, x.y), fmaxf(x.z, x.w));
    #pragma unroll
    for (int s = 32; s >= 1; s >>= 1) mx = fmaxf(mx, __shfl_xor(mx, s));
    if ((t & 63) == 0) wred[w] = mx;
    __syncthreads();
    float M = fmaxf(fmaxf(wred[0], wred[1]), fmaxf(wred[2], wred[3]));
    float4 e;
    e.x = __expf(x.x - M); e.y = __expf(x.y - M);
    e.z = __expf(x.z - M); e.w = __expf(x.w - M);
    float sm = e.x + e.y + e.z + e.w;
    #pragma unroll
    for (int s = 32; s >= 1; s >>= 1) sm += __shfl_xor(sm, s);
    if ((t & 63) == 0) wred[4 + w] = sm;
    __syncthreads();
    float inv = 1.0f / (wred[4] + wred[5] + wred[6] + wred[7]);
    if (act) {
        float4 rr;
        rr.x = e.x * inv; rr.y = e.y * inv; rr.z = e.z * inv; rr.w = e.w * inv;
        *(float4*)&p[t * 4] = rr;
    }
}

extern "C" void kernel_launch(void* const* d_in, const int* in_sizes, int n_in,
                              void* d_out, int out_size, void* d_ws, size_t ws_size,
                              hipStream_t stream)
{
    const float* pref  = (const float*)d_in[0];
    const float* nodes = (const float*)d_in[1];
    const float* q1    = (const float*)d_in[2];
    const float* lastn = (const float*)d_in[3];
    const float* mask  = (const float*)d_in[4];
    const float* fc1_w = (const float*)d_in[5];
    const float* fc1_b = (const float*)d_in[6];
    const float* fc2_w = (const float*)d_in[7];
    const float* fc2_b = (const float*)d_in[8];
    const float* fc3_w = (const float*)d_in[9];
    const float* fc3_b = (const float*)d_in[10];
    const float* wqf   = (const float*)d_in[11];
    const float* wql   = (const float*)d_in[12];
    const float* wk    = (const float*)d_in[13];
    const float* wv    = (const float*)d_in[14];
    const float* wc    = (const float*)d_in[15];
    float* out = (float*)d_out;
    float* ws  = (float*)d_ws;

    float* W5 = ws;                                   // 5*16384 = 81920
    float* Kb = ws + 81920;                           // 8*1196*128
    float* Vb = Kb + (long)BB * NKEY * EMB;
    float* Qb = Vb + (long)BB * NKEY * EMB;           // 8*1000*128
    float* OC = Qb + (long)BB * POMO * EMB;
    float* MH = OC + (long)BB * POMO * EMB;
    float* gmid = MH + (long)BB * POMO * EMB;         // 16 floats, ~22.4 MB total

    float* pacc = out;                 // d_out (32 MB) as partial scratch
    float* pl   = out + PACC_FLOATS;   // fully overwritten by logits later

    hipLaunchKernelGGL(hyper_mid_kernel, dim3(1), dim3(256), 0, stream,
                       pref, fc1_w, fc1_b, fc2_w, fc2_b, fc3_w, fc3_b, gmid);
    hipLaunchKernelGGL(hyper_expand_kernel, dim3(40), dim3(256), 0, stream,
                       gmid, wqf, wql, wk, wv, wc, W5);
    hipLaunchKernelGGL(kv_proj_kernel, dim3(299), dim3(256), 0, stream, nodes, W5, Kb, Vb);
    hipLaunchKernelGGL(q_proj_kernel, dim3(250), dim3(256), 0, stream, q1, lastn, W5, Qb);
    hipLaunchKernelGGL(attn_split_kernel, dim3(8, RTILES, SCH), dim3(128), 0, stream,
                       Kb, Vb, Qb, mask, pacc, pl);
    hipLaunchKernelGGL(attn_merge_kernel, dim3(8, RTILES), dim3(256), 0, stream, pacc, pl, OC);
    hipLaunchKernelGGL(combine_kernel, dim3(250), dim3(256), 0, stream, OC, W5, MH);
    hipLaunchKernelGGL(logits_kernel, dim3(8, 8, 8), dim3(256), 0, stream, MH, nodes, mask, out);
    hipLaunchKernelGGL(softmax_kernel, dim3(8000), dim3(256), 0, stream, out);
}

// Round 12
// 257.762 us; speedup vs baseline: 8.8136x; 1.2222x over previous
//
#include <hip/hip_runtime.h>
#include <math.h>

#define EMB 128
#define NH 8
#define DH 16
#define HID 256
#define NODE 1000
#define PATCH 196
#define NKEY (NODE + PATCH)   // 1196
#define BB 8
#define POMO 1000
#define KT 16                  // attention key tile
#define SCH 7                  // key-split chunks
#define CKEYS 172              // keys per chunk (last = 164)
#define RTILES 32              // 32-row tiles
#define TROWS 32

// partial buffers alias d_out (8M floats):
// pacc: [b][tile][chunk][row32][h][16] = 8*32*7*32*8*16 = 7,340,032 floats
// pl  : [b][tile][chunk][h][row32]     = 8*32*7*8*32    =   458,752 floats
#define PACC_FLOATS 7340032L

__device__ __forceinline__ float tanh10(float x) {
    float e = __expf(2.0f * x);
    return 10.0f * (1.0f - 2.0f / (e + 1.0f));
}

// ---------------- hypernet stage 1: pref -> mid[15] -------------------------
__global__ __launch_bounds__(256) void hyper_mid_kernel(
    const float* __restrict__ pref,
    const float* __restrict__ fc1_w, const float* __restrict__ fc1_b,
    const float* __restrict__ fc2_w, const float* __restrict__ fc2_b,
    const float* __restrict__ fc3_w, const float* __restrict__ fc3_b,
    float* __restrict__ gmid)
{
    __shared__ float h1[HID];
    __shared__ float h2[HID];
    int t = threadIdx.x;
    float p0 = pref[0], p1 = pref[1], p2 = pref[2];
    h1[t] = fc1_b[t] + p0 * fc1_w[t * 3 + 0] + p1 * fc1_w[t * 3 + 1] + p2 * fc1_w[t * 3 + 2];
    __syncthreads();
    {
        float s = fc2_b[t];
        const float4* w4 = (const float4*)(fc2_w + t * HID);
        const float4* h4 = (const float4*)h1;
        for (int j = 0; j < HID / 4; ++j) {
            float4 w = w4[j], x = h4[j];
            s += x.x * w.x + x.y * w.y + x.z * w.z + x.w * w.w;
        }
        h2[t] = s;
    }
    __syncthreads();
    if (t < 15) {
        float s = fc3_b[t];
        const float4* w4 = (const float4*)(fc3_w + t * HID);
        const float4* h4 = (const float4*)h2;
        for (int j = 0; j < HID / 4; ++j) {
            float4 w = w4[j], x = h4[j];
            s += x.x * w.x + x.y * w.y + x.z * w.z + x.w * w.w;
        }
        gmid[t] = s;
    }
}

// ---------------- hypernet stage 2: mid -> 5 weight matrices ----------------
__global__ __launch_bounds__(256) void hyper_expand_kernel(
    const float* __restrict__ gmid,
    const float* __restrict__ wqf, const float* __restrict__ wql,
    const float* __restrict__ wk,  const float* __restrict__ wv,
    const float* __restrict__ wc,  float* __restrict__ W5)
{
    int id = blockIdx.x;                 // 40 blocks: 5 mats x 8 segments
    int mat = id >> 3;
    int x0 = (id & 7) * 2048 + threadIdx.x * 8;
    const float* w = (mat == 0) ? wqf : (mat == 1) ? wql : (mat == 2) ? wk : (mat == 3) ? wv : wc;
    float m0 = gmid[mat * 3 + 0], m1 = gmid[mat * 3 + 1], m2 = gmid[mat * 3 + 2];
    float* dst = W5 + mat * EMB * EMB;
    #pragma unroll
    for (int i = 0; i < 8; ++i) {
        int x = x0 + i;
        dst[x] = m0 * w[x * 3 + 0] + m1 * w[x * 3 + 1] + m2 * w[x * 3 + 2];
    }
}

// ---------------- fused K,V + Q projections (one launch) --------------------
// blocks 0..298: K/V proj of encoded_nodes; blocks 299..548: Q proj.
__global__ __launch_bounds__(256) void proj_kernel(
    const float* __restrict__ nodes, const float* __restrict__ q1,
    const float* __restrict__ lastn, const float* __restrict__ W5,
    float* __restrict__ Kb, float* __restrict__ Vb, float* __restrict__ Qb)
{
    __shared__ float xa[32][EMB];
    __shared__ float xb[32][EMB];
    int t = threadIdx.x;
    int bid = blockIdx.x;
    if (bid < 299) {
        // ---- K/V path ----
        long r0 = (long)bid * 32;               // over BB*NKEY = 9568
        const float4* s4 = (const float4*)(nodes + r0 * EMB);
        float4* x4p = (float4*)&xa[0][0];
        for (int i = t; i < 32 * EMB / 4; i += 256) x4p[i] = s4[i];
        __syncthreads();
        int o = t;
        const float* W = (o < EMB) ? (W5 + 2 * EMB * EMB + o * EMB)
                                   : (W5 + 3 * EMB * EMB + (o - EMB) * EMB);
        float acc[32];
        #pragma unroll
        for (int r = 0; r < 32; ++r) acc[r] = 0.f;
        for (int e = 0; e < EMB; e += 4) {
            float4 w4 = *(const float4*)&W[e];
            #pragma unroll
            for (int r = 0; r < 32; ++r) {
                float4 x4 = *(const float4*)&xa[r][e];
                acc[r] += x4.x * w4.x + x4.y * w4.y + x4.z * w4.z + x4.w * w4.w;
            }
        }
        float* dst = (o < EMB) ? (Kb + r0 * EMB + o) : (Vb + r0 * EMB + (o - EMB));
        #pragma unroll
        for (int r = 0; r < 32; ++r) dst[(long)r * EMB] = acc[r];
    } else {
        // ---- Q path: q1@Wqf.T + last@Wql.T ----
        long r0 = (long)(bid - 299) * 32;       // over 8000
        const float4* a4 = (const float4*)(q1 + r0 * EMB);
        const float4* b4 = (const float4*)(lastn + r0 * EMB);
        float4* xap = (float4*)&xa[0][0];
        float4* xbp = (float4*)&xb[0][0];
        for (int i = t; i < 32 * EMB / 4; i += 256) { xap[i] = a4[i]; xbp[i] = b4[i]; }
        __syncthreads();
        int o = t & 127;
        int rbase = (t >> 7) * 16;
        const float* Wf = W5 + 0 * EMB * EMB + o * EMB;
        const float* Wl = W5 + 1 * EMB * EMB + o * EMB;
        float acc[16];
        #pragma unroll
        for (int r = 0; r < 16; ++r) acc[r] = 0.f;
        for (int e = 0; e < EMB; e += 4) {
            float4 wf = *(const float4*)&Wf[e];
            float4 wl = *(const float4*)&Wl[e];
            #pragma unroll
            for (int r = 0; r < 16; ++r) {
                float4 va = *(const float4*)&xa[rbase + r][e];
                float4 vb = *(const float4*)&xb[rbase + r][e];
                acc[r] += va.x * wf.x + va.y * wf.y + va.z * wf.z + va.w * wf.w
                        + vb.x * wl.x + vb.y * wl.y + vb.z * wl.z + vb.w * wl.w;
            }
        }
        #pragma unroll
        for (int r = 0; r < 16; ++r) Qb[(r0 + rbase + r) * EMB + o] = acc[r];
    }
}

// ---------------- fused masked MHA, key-split, NO-max-shift flash -----------
// (r5/r11's exact verified 128-VGPR kernel; only SCH=7 + jm-window mask.)
// grid (8, 32, 7): x=b (XCD-aligned), y=32-row tile, z=key chunk.
// block 128: h = t>>4, rr = t&15; thread owns rows {2rr, 2rr+1}.
__global__ __launch_bounds__(128, 2) void attn_split_kernel(
    const float* __restrict__ Kb, const float* __restrict__ Vb,
    const float* __restrict__ Qb, const float* __restrict__ mask,
    float* __restrict__ pacc, float* __restrict__ pl)
{
    __shared__ float ks[KT][EMB];
    __shared__ float vs[KT][EMB];
    int t = threadIdx.x;
    int b = blockIdx.x;
    int tile = blockIdx.y;
    int c = blockIdx.z;
    int rr = t & 15;
    int h = t >> 4;
    int row0 = tile * TROWS + rr * 2;
    bool active = (row0 < POMO);
    int qrow = active ? row0 : (POMO - 2);     // clamped; stores guarded
    int kstart = c * CKEYS;
    int kend = kstart + CKEYS; if (kend > NKEY) kend = NKEY;

    float q0[DH], q1r[DH];
    {
        const float4* qp0 = (const float4*)(Qb + ((long)b * POMO + qrow) * EMB + h * DH);
        const float4* qp1 = (const float4*)(Qb + ((long)b * POMO + qrow + 1) * EMB + h * DH);
        #pragma unroll
        for (int i = 0; i < 4; ++i) {
            float4 v = qp0[i];   // pre-scale by 1/sqrt(16): s = q.k + mask
            q0[4*i+0] = v.x*0.25f; q0[4*i+1] = v.y*0.25f;
            q0[4*i+2] = v.z*0.25f; q0[4*i+3] = v.w*0.25f;
            float4 w = qp1[i];
            q1r[4*i+0] = w.x*0.25f; q1r[4*i+1] = w.y*0.25f;
            q1r[4*i+2] = w.z*0.25f; q1r[4*i+3] = w.w*0.25f;
        }
    }
    float acc0[DH], acc1[DH];
    #pragma unroll
    for (int i = 0; i < DH; ++i) { acc0[i] = 0.f; acc1[i] = 0.f; }
    float l0 = 0.f, l1 = 0.f;

    const float4* ksrc = (const float4*)(Kb + (long)b * NKEY * EMB);
    const float4* vsrc = (const float4*)(Vb + (long)b * NKEY * EMB);
    const int max4 = NKEY * (EMB / 4) - 1;
    const float* mrow0 = mask + ((long)b * POMO + qrow) * NODE;
    const float* mrow1 = mrow0 + NODE;

    for (int t0 = kstart; t0 < kend; t0 += KT) {
        int valid = kend - t0; if (valid > KT) valid = KT;   // 16, 12 or 4
        __syncthreads();
        {   // stage K,V tile via registers (L2-friendly), clamped source
            float4* kd = (float4*)&ks[0][0];
            float4* vd = (float4*)&vs[0][0];
            int base4 = t0 * (EMB / 4);
            #pragma unroll
            for (int u = 0; u < 4; ++u) {
                int i = t + u * 128;
                int src = base4 + i; if (src > max4) src = max4;
                kd[i] = ksrc[src];
                vd[i] = vsrc[src];
            }
        }
        __syncthreads();

        // float4 key-groups carrying mask: j4 < jm (NODE, t0, valid all
        // multiples of 4 -> groups never straddle the node/patch boundary)
        int jm = 0;
        if (t0 < NODE) {
            int lim = NODE - t0; if (lim > valid) lim = valid;
            jm = lim >> 2;
        }
        float mk0[KT], mk1[KT];
        {
            const float4* mp0 = (const float4*)(mrow0 + t0);
            const float4* mp1 = (const float4*)(mrow1 + t0);
            #pragma unroll
            for (int j4 = 0; j4 < KT / 4; ++j4) {
                float4 a = (j4 < jm) ? mp0[j4] : make_float4(0,0,0,0);
                float4 bm = (j4 < jm) ? mp1[j4] : make_float4(0,0,0,0);
                mk0[4*j4+0]=a.x;  mk0[4*j4+1]=a.y;  mk0[4*j4+2]=a.z;  mk0[4*j4+3]=a.w;
                mk1[4*j4+0]=bm.x; mk1[4*j4+1]=bm.y; mk1[4*j4+2]=bm.z; mk1[4*j4+3]=bm.w;
            }
        }

#define INNER(TAIL)                                                          \
        _Pragma("unroll")                                                    \
        for (int j = 0; j < KT; ++j) {                                       \
            float s0 = mk0[j], s1 = mk1[j];                                  \
            _Pragma("unroll")                                                \
            for (int e = 0; e < DH; e += 4) {                                \
                float4 k4 = *(const float4*)&ks[j][h * DH + e];              \
                s0 += q0[e]*k4.x + q0[e+1]*k4.y + q0[e+2]*k4.z + q0[e+3]*k4.w; \
                s1 += q1r[e]*k4.x + q1r[e+1]*k4.y + q1r[e+2]*k4.z + q1r[e+3]*k4.w; \
            }                                                                \
            float p0 = __expf(s0), p1 = __expf(s1);                          \
            if (TAIL && j >= valid) { p0 = 0.f; p1 = 0.f; }                  \
            l0 += p0; l1 += p1;                                              \
            _Pragma("unroll")                                                \
            for (int e = 0; e < DH; e += 4) {                                \
                float4 v4 = *(const float4*)&vs[j][h * DH + e];              \
                acc0[e+0] += p0*v4.x; acc0[e+1] += p0*v4.y;                  \
                acc0[e+2] += p0*v4.z; acc0[e+3] += p0*v4.w;                  \
                acc1[e+0] += p1*v4.x; acc1[e+1] += p1*v4.y;                  \
                acc1[e+2] += p1*v4.z; acc1[e+3] += p1*v4.w;                  \
            }                                                                \
        }
        if (valid == KT) { INNER(false) } else { INNER(true) }
#undef INNER
    }
    if (active) {
        long cb = ((long)(b * RTILES + tile) * SCH + c);
        // pacc: [cb][row32][h][16] -- dense 64B records, full-line wave stores
        long rec0 = ((cb * TROWS + rr * 2) * NH + h) * 16;
        long rec1 = rec0 + (long)NH * 16;
        #pragma unroll
        for (int i = 0; i < 4; ++i) {
            *(float4*)&pacc[rec0 + 4*i] =
                make_float4(acc0[4*i], acc0[4*i+1], acc0[4*i+2], acc0[4*i+3]);
            *(float4*)&pacc[rec1 + 4*i] =
                make_float4(acc1[4*i], acc1[4*i+1], acc1[4*i+2], acc1[4*i+3]);
        }
        // pl: [cb][h][row32] -- contiguous per (cb,h)
        long plrec = (cb * NH + h) * TROWS + rr * 2;
        *(float2*)&pl[plrec] = make_float2(l0, l1);
    }
}

// ---------------- fused merge + combine: partials -> MH ---------------------
// grid (8, 32), 256 threads. Phase 1 (t = rt*8 + h): merge chunk partials
// for row rt, head h -> normalized oc row in LDS. Phase 2: combine GEMM
// mh = oc @ Wc.T for the 32 rows. Saves the OC global round-trip + a launch.
__global__ __launch_bounds__(256) void merge_combine_kernel(
    const float* __restrict__ pacc, const float* __restrict__ pl,
    const float* __restrict__ W5, float* __restrict__ MH)
{
    __shared__ float xs[32][EMB];
    int t = threadIdx.x;
    int b = blockIdx.x, tile = blockIdx.y;
    {   // phase 1: merge
        int rt = t >> 3, h = t & 7;
        int row = tile * TROWS + rt;
        float o[16];
        #pragma unroll
        for (int i = 0; i < 16; ++i) o[i] = 0.f;
        if (row < POMO) {
            long cb0 = (long)(b * RTILES + tile) * SCH;
            const long cs_acc = (long)TROWS * NH * 16;   // 4096 floats/chunk
            long abase = cb0 * cs_acc + ((long)rt * NH + h) * 16;
            const long cs_pl = (long)NH * TROWS;         // 256 floats/chunk
            long lbase = cb0 * cs_pl + (long)h * TROWS + rt;
            float L = 0.f;
            #pragma unroll
            for (int c = 0; c < SCH; ++c) {
                L += pl[lbase + c * cs_pl];
                #pragma unroll
                for (int i4 = 0; i4 < 4; ++i4) {
                    float4 a = *(const float4*)&pacc[abase + c * cs_acc + 4 * i4];
                    o[4*i4+0] += a.x; o[4*i4+1] += a.y;
                    o[4*i4+2] += a.z; o[4*i4+3] += a.w;
                }
            }
            float inv = 1.0f / L;
            #pragma unroll
            for (int i = 0; i < 16; ++i) o[i] *= inv;
        }
        float* xp = &xs[rt][h * DH];
        #pragma unroll
        for (int i4 = 0; i4 < 4; ++i4)
            *(float4*)&xp[4*i4] = make_float4(o[4*i4], o[4*i4+1], o[4*i4+2], o[4*i4+3]);
    }
    __syncthreads();
    {   // phase 2: combine (mh = oc @ Wc.T)
        int o = t & 127;
        int rbase = (t >> 7) * 16;
        const float* W = W5 + 4 * EMB * EMB + o * EMB;
        float acc[16];
        #pragma unroll
        for (int r = 0; r < 16; ++r) acc[r] = 0.f;
        for (int e = 0; e < EMB; e += 4) {
            float4 w4 = *(const float4*)&W[e];
            #pragma unroll
            for (int r = 0; r < 16; ++r) {
                float4 x4 = *(const float4*)&xs[rbase + r][e];
                acc[r] += x4.x * w4.x + x4.y * w4.y + x4.z * w4.z + x4.w * w4.w;
            }
        }
        long row0 = (long)tile * TROWS + rbase;
        #pragma unroll
        for (int r = 0; r < 16; ++r) {
            long row = row0 + r;
            if (row < POMO)
                MH[((long)b * POMO + row) * EMB + o] = acc[r];
        }
    }
}

// ---------------- logits: exp(10*tanh((mh@nodes.T)/sqrt128) + mask) ---------
// Writes UNNORMALIZED softmax numerators (exp fused; logits in [-10,10],
// masked -> exp(-1e30)=0). normalize_kernel divides by the row sum.
__global__ __launch_bounds__(256, 2) void logits_kernel(
    const float* __restrict__ MH, const float* __restrict__ nodes,
    const float* __restrict__ mask, float* __restrict__ out)
{
    __shared__ float As[32][128];   // [e][n] 16 KB
    __shared__ float Bs[32][192];   // [e][16 groups * 12] 24 KB
    int t = threadIdx.x;
    int b = blockIdx.x;
    int n0 = blockIdx.y * 128;      // pomo rows
    int m0 = blockIdx.z * 128;      // node cols
    int ci = t & 15, ri = t >> 4;

    float acc[8][8];
    #pragma unroll
    for (int i = 0; i < 8; ++i)
        #pragma unroll
        for (int j = 0; j < 8; ++j) acc[i][j] = 0.f;

    int ln = t & 127;
    int eh = (t >> 7) * 16;
    int arow = n0 + ln; if (arow >= POMO) arow = POMO - 1;   // clamp reads
    const float* Arow = MH + ((long)b * POMO + arow) * EMB;
    const float* Brow = nodes + ((long)b * NKEY + m0 + ln) * EMB;  // m0+127<NKEY
    int bcol = (ln >> 3) * 12 + (ln & 7);

    for (int e0 = 0; e0 < EMB; e0 += 32) {
        if (e0) __syncthreads();
        #pragma unroll
        for (int u = 0; u < 4; ++u) {
            int e = eh + u * 4;
            float4 a4 = *(const float4*)&Arow[e0 + e];
            float4 b4 = *(const float4*)&Brow[e0 + e];
            As[e + 0][ln] = a4.x; As[e + 1][ln] = a4.y;
            As[e + 2][ln] = a4.z; As[e + 3][ln] = a4.w;
            Bs[e + 0][bcol] = b4.x; Bs[e + 1][bcol] = b4.y;
            Bs[e + 2][bcol] = b4.z; Bs[e + 3][bcol] = b4.w;
        }
        __syncthreads();
        #pragma unroll
        for (int e = 0; e < 32; ++e) {
            float4 a0 = *(const float4*)&As[e][ri * 8];
            float4 a1 = *(const float4*)&As[e][ri * 8 + 4];
            float4 b0 = *(const float4*)&Bs[e][ci * 12];
            float4 b1 = *(const float4*)&Bs[e][ci * 12 + 4];
            float av[8] = {a0.x, a0.y, a0.z, a0.w, a1.x, a1.y, a1.z, a1.w};
            float bv[8] = {b0.x, b0.y, b0.z, b0.w, b1.x, b1.y, b1.z, b1.w};
            #pragma unroll
            for (int i = 0; i < 8; ++i)
                #pragma unroll
                for (int j = 0; j < 8; ++j)
                    acc[i][j] += av[i] * bv[j];
        }
    }
    const float inv = 0.08838834764831845f;  // 1/sqrt(128)
    bool mfull = (m0 + 127 < NODE);
    int m = m0 + ci * 8;
    #pragma unroll
    for (int i = 0; i < 8; ++i) {
        int n = n0 + ri * 8 + i;
        if (n >= POMO) continue;
        long rbase = ((long)b * POMO + n) * NODE;
        if (mfull) {
            #pragma unroll
            for (int j4 = 0; j4 < 2; ++j4) {
                float4 mk = *(const float4*)&mask[rbase + m + j4 * 4];
                float4 r;
                r.x = __expf(tanh10(acc[i][j4*4+0] * inv) + mk.x);
                r.y = __expf(tanh10(acc[i][j4*4+1] * inv) + mk.y);
                r.z = __expf(tanh10(acc[i][j4*4+2] * inv) + mk.z);
                r.w = __expf(tanh10(acc[i][j4*4+3] * inv) + mk.w);
                *(float4*)&out[rbase + m + j4 * 4] = r;
            }
        } else {
            #pragma unroll
            for (int j = 0; j < 8; ++j) {
                int mm = m + j;
                if (mm < NODE)
                    out[rbase + mm] = __expf(tanh10(acc[i][j] * inv) + mask[rbase + mm]);
            }
        }
    }
}

// ---------------- normalize: divide row by its sum (exp already applied) ----
__global__ __launch_bounds__(256) void normalize_kernel(float* __restrict__ out)
{
    __shared__ float wred[4];
    int t = threadIdx.x;
    int w = t >> 6;
    float* p = out + (long)blockIdx.x * NODE;
    bool act = t < 250;
    float4 x = act ? *(const float4*)&p[t * 4] : make_float4(0.f, 0.f, 0.f, 0.f);
    float sm = x.x + x.y + x.z + x.w;
    #pragma unroll
    for (int s = 32; s >= 1; s >>= 1) sm += __shfl_xor(sm, s);
    if ((t & 63) == 0) wred[w] = sm;
    __syncthreads();
    float inv = 1.0f / (wred[0] + wred[1] + wred[2] + wred[3]);
    if (act) {
        float4 rr;
        rr.x = x.x * inv; rr.y = x.y * inv; rr.z = x.z * inv; rr.w = x.w * inv;
        *(float4*)&p[t * 4] = rr;
    }
}

extern "C" void kernel_launch(void* const* d_in, const int* in_sizes, int n_in,
                              void* d_out, int out_size, void* d_ws, size_t ws_size,
                              hipStream_t stream)
{
    const float* pref  = (const float*)d_in[0];
    const float* nodes = (const float*)d_in[1];
    const float* q1    = (const float*)d_in[2];
    const float* lastn = (const float*)d_in[3];
    const float* mask  = (const float*)d_in[4];
    const float* fc1_w = (const float*)d_in[5];
    const float* fc1_b = (const float*)d_in[6];
    const float* fc2_w = (const float*)d_in[7];
    const float* fc2_b = (const float*)d_in[8];
    const float* fc3_w = (const float*)d_in[9];
    const float* fc3_b = (const float*)d_in[10];
    const float* wqf   = (const float*)d_in[11];
    const float* wql   = (const float*)d_in[12];
    const float* wk    = (const float*)d_in[13];
    const float* wv    = (const float*)d_in[14];
    const float* wc    = (const float*)d_in[15];
    float* out = (float*)d_out;
    float* ws  = (float*)d_ws;

    float* W5 = ws;                                   // 5*16384 = 81920
    float* Kb = ws + 81920;                           // 8*1196*128
    float* Vb = Kb + (long)BB * NKEY * EMB;
    float* Qb = Vb + (long)BB * NKEY * EMB;           // 8*1000*128
    float* MH = Qb + (long)BB * POMO * EMB;
    float* gmid = MH + (long)BB * POMO * EMB;         // 16 floats, ~18.3 MB total

    float* pacc = out;                 // d_out (8M floats) as partial scratch
    float* pl   = out + PACC_FLOATS;   // 7.34M + 0.46M = 7.8M <= 8M; fully
                                       // overwritten by logits afterwards

    hipLaunchKernelGGL(hyper_mid_kernel, dim3(1), dim3(256), 0, stream,
                       pref, fc1_w, fc1_b, fc2_w, fc2_b, fc3_w, fc3_b, gmid);
    hipLaunchKernelGGL(hyper_expand_kernel, dim3(40), dim3(256), 0, stream,
                       gmid, wqf, wql, wk, wv, wc, W5);
    hipLaunchKernelGGL(proj_kernel, dim3(549), dim3(256), 0, stream,
                       nodes, q1, lastn, W5, Kb, Vb, Qb);
    hipLaunchKernelGGL(attn_split_kernel, dim3(8, RTILES, SCH), dim3(128), 0, stream,
                       Kb, Vb, Qb, mask, pacc, pl);
    hipLaunchKernelGGL(merge_combine_kernel, dim3(8, RTILES), dim3(256), 0, stream,
                       pacc, pl, W5, MH);
    hipLaunchKernelGGL(logits_kernel, dim3(8, 8, 8), dim3(256), 0, stream,
                       MH, nodes, mask, out);
    hipLaunchKernelGGL(normalize_kernel, dim3(8000), dim3(256), 0, stream, out);
}

// Round 13
// 244.689 us; speedup vs baseline: 9.2844x; 1.0534x over previous
//
#include <hip/hip_runtime.h>
#include <math.h>

#define EMB 128
#define NH 8
#define DH 16
#define HID 256
#define NODE 1000
#define PATCH 196
#define NKEY (NODE + PATCH)   // 1196
#define BB 8
#define POMO 1000
#define KT 16                  // attention key tile
#define SCH 7                  // key-split chunks
#define CKEYS 172              // keys per chunk (last = 164)
#define RTILES 32              // 32-row tiles
#define TROWS 32

// partial buffers alias d_out (8M floats):
// pacc: [b][tile][chunk][row32][h][16] = 8*32*7*32*8*16 = 7,340,032 floats
// pl  : [b][tile][chunk][h][row32]     = 8*32*7*8*32    =   458,752 floats
#define PACC_FLOATS 7340032L

__device__ __forceinline__ float tanh10(float x) {
    float e = __expf(2.0f * x);
    return 10.0f * (1.0f - 2.0f / (e + 1.0f));
}

// ---------------- hypernet stage 1: pref -> mid[15] -------------------------
__global__ __launch_bounds__(256) void hyper_mid_kernel(
    const float* __restrict__ pref,
    const float* __restrict__ fc1_w, const float* __restrict__ fc1_b,
    const float* __restrict__ fc2_w, const float* __restrict__ fc2_b,
    const float* __restrict__ fc3_w, const float* __restrict__ fc3_b,
    float* __restrict__ gmid)
{
    __shared__ float h1[HID];
    __shared__ float h2[HID];
    int t = threadIdx.x;
    float p0 = pref[0], p1 = pref[1], p2 = pref[2];
    h1[t] = fc1_b[t] + p0 * fc1_w[t * 3 + 0] + p1 * fc1_w[t * 3 + 1] + p2 * fc1_w[t * 3 + 2];
    __syncthreads();
    {
        float s = fc2_b[t];
        const float4* w4 = (const float4*)(fc2_w + t * HID);
        const float4* h4 = (const float4*)h1;
        for (int j = 0; j < HID / 4; ++j) {
            float4 w = w4[j], x = h4[j];
            s += x.x * w.x + x.y * w.y + x.z * w.z + x.w * w.w;
        }
        h2[t] = s;
    }
    __syncthreads();
    if (t < 15) {
        float s = fc3_b[t];
        const float4* w4 = (const float4*)(fc3_w + t * HID);
        const float4* h4 = (const float4*)h2;
        for (int j = 0; j < HID / 4; ++j) {
            float4 w = w4[j], x = h4[j];
            s += x.x * w.x + x.y * w.y + x.z * w.z + x.w * w.w;
        }
        gmid[t] = s;
    }
}

// ---------------- hypernet stage 2: mid -> 5 weight matrices ----------------
__global__ __launch_bounds__(256) void hyper_expand_kernel(
    const float* __restrict__ gmid,
    const float* __restrict__ wqf, const float* __restrict__ wql,
    const float* __restrict__ wk,  const float* __restrict__ wv,
    const float* __restrict__ wc,  float* __restrict__ W5)
{
    int id = blockIdx.x;                 // 40 blocks: 5 mats x 8 segments
    int mat = id >> 3;
    int x0 = (id & 7) * 2048 + threadIdx.x * 8;
    const float* w = (mat == 0) ? wqf : (mat == 1) ? wql : (mat == 2) ? wk : (mat == 3) ? wv : wc;
    float m0 = gmid[mat * 3 + 0], m1 = gmid[mat * 3 + 1], m2 = gmid[mat * 3 + 2];
    float* dst = W5 + mat * EMB * EMB;
    #pragma unroll
    for (int i = 0; i < 8; ++i) {
        int x = x0 + i;
        dst[x] = m0 * w[x * 3 + 0] + m1 * w[x * 3 + 1] + m2 * w[x * 3 + 2];
    }
}

// ---------------- fused K,V + Q projections (one launch) --------------------
__global__ __launch_bounds__(256) void proj_kernel(
    const float* __restrict__ nodes, const float* __restrict__ q1,
    const float* __restrict__ lastn, const float* __restrict__ W5,
    float* __restrict__ Kb, float* __restrict__ Vb, float* __restrict__ Qb)
{
    __shared__ float xa[32][EMB];
    __shared__ float xb[32][EMB];
    int t = threadIdx.x;
    int bid = blockIdx.x;
    if (bid < 299) {
        // ---- K/V path ----
        long r0 = (long)bid * 32;               // over BB*NKEY = 9568
        const float4* s4 = (const float4*)(nodes + r0 * EMB);
        float4* x4p = (float4*)&xa[0][0];
        for (int i = t; i < 32 * EMB / 4; i += 256) x4p[i] = s4[i];
        __syncthreads();
        int o = t;
        const float* W = (o < EMB) ? (W5 + 2 * EMB * EMB + o * EMB)
                                   : (W5 + 3 * EMB * EMB + (o - EMB) * EMB);
        float acc[32];
        #pragma unroll
        for (int r = 0; r < 32; ++r) acc[r] = 0.f;
        for (int e = 0; e < EMB; e += 4) {
            float4 w4 = *(const float4*)&W[e];
            #pragma unroll
            for (int r = 0; r < 32; ++r) {
                float4 x4 = *(const float4*)&xa[r][e];
                acc[r] += x4.x * w4.x + x4.y * w4.y + x4.z * w4.z + x4.w * w4.w;
            }
        }
        float* dst = (o < EMB) ? (Kb + r0 * EMB + o) : (Vb + r0 * EMB + (o - EMB));
        #pragma unroll
        for (int r = 0; r < 32; ++r) dst[(long)r * EMB] = acc[r];
    } else {
        // ---- Q path: q1@Wqf.T + last@Wql.T ----
        long r0 = (long)(bid - 299) * 32;       // over 8000
        const float4* a4 = (const float4*)(q1 + r0 * EMB);
        const float4* b4 = (const float4*)(lastn + r0 * EMB);
        float4* xap = (float4*)&xa[0][0];
        float4* xbp = (float4*)&xb[0][0];
        for (int i = t; i < 32 * EMB / 4; i += 256) { xap[i] = a4[i]; xbp[i] = b4[i]; }
        __syncthreads();
        int o = t & 127;
        int rbase = (t >> 7) * 16;
        const float* Wf = W5 + 0 * EMB * EMB + o * EMB;
        const float* Wl = W5 + 1 * EMB * EMB + o * EMB;
        float acc[16];
        #pragma unroll
        for (int r = 0; r < 16; ++r) acc[r] = 0.f;
        for (int e = 0; e < EMB; e += 4) {
            float4 wf = *(const float4*)&Wf[e];
            float4 wl = *(const float4*)&Wl[e];
            #pragma unroll
            for (int r = 0; r < 16; ++r) {
                float4 va = *(const float4*)&xa[rbase + r][e];
                float4 vb = *(const float4*)&xb[rbase + r][e];
                acc[r] += va.x * wf.x + va.y * wf.y + va.z * wf.z + va.w * wf.w
                        + vb.x * wl.x + vb.y * wl.y + vb.z * wl.z + vb.w * wl.w;
            }
        }
        #pragma unroll
        for (int r = 0; r < 16; ++r) Qb[(r0 + rbase + r) * EMB + o] = acc[r];
    }
}

// ---------------- fused masked MHA, key-split, NO-max-shift flash -----------
// (verified 128-VGPR kernel; + s_setprio around the inner loop (T5))
// grid (8, 32, 7): x=b (XCD-aligned), y=32-row tile, z=key chunk.
__global__ __launch_bounds__(128, 2) void attn_split_kernel(
    const float* __restrict__ Kb, const float* __restrict__ Vb,
    const float* __restrict__ Qb, const float* __restrict__ mask,
    float* __restrict__ pacc, float* __restrict__ pl)
{
    __shared__ float ks[KT][EMB];
    __shared__ float vs[KT][EMB];
    int t = threadIdx.x;
    int b = blockIdx.x;
    int tile = blockIdx.y;
    int c = blockIdx.z;
    int rr = t & 15;
    int h = t >> 4;
    int row0 = tile * TROWS + rr * 2;
    bool active = (row0 < POMO);
    int qrow = active ? row0 : (POMO - 2);     // clamped; stores guarded
    int kstart = c * CKEYS;
    int kend = kstart + CKEYS; if (kend > NKEY) kend = NKEY;

    float q0[DH], q1r[DH];
    {
        const float4* qp0 = (const float4*)(Qb + ((long)b * POMO + qrow) * EMB + h * DH);
        const float4* qp1 = (const float4*)(Qb + ((long)b * POMO + qrow + 1) * EMB + h * DH);
        #pragma unroll
        for (int i = 0; i < 4; ++i) {
            float4 v = qp0[i];   // pre-scale by 1/sqrt(16): s = q.k + mask
            q0[4*i+0] = v.x*0.25f; q0[4*i+1] = v.y*0.25f;
            q0[4*i+2] = v.z*0.25f; q0[4*i+3] = v.w*0.25f;
            float4 w = qp1[i];
            q1r[4*i+0] = w.x*0.25f; q1r[4*i+1] = w.y*0.25f;
            q1r[4*i+2] = w.z*0.25f; q1r[4*i+3] = w.w*0.25f;
        }
    }
    float acc0[DH], acc1[DH];
    #pragma unroll
    for (int i = 0; i < DH; ++i) { acc0[i] = 0.f; acc1[i] = 0.f; }
    float l0 = 0.f, l1 = 0.f;

    const float4* ksrc = (const float4*)(Kb + (long)b * NKEY * EMB);
    const float4* vsrc = (const float4*)(Vb + (long)b * NKEY * EMB);
    const int max4 = NKEY * (EMB / 4) - 1;
    const float* mrow0 = mask + ((long)b * POMO + qrow) * NODE;
    const float* mrow1 = mrow0 + NODE;

    for (int t0 = kstart; t0 < kend; t0 += KT) {
        int valid = kend - t0; if (valid > KT) valid = KT;   // 16, 12 or 4
        __syncthreads();
        {   // stage K,V tile via registers (L2-friendly), clamped source
            float4* kd = (float4*)&ks[0][0];
            float4* vd = (float4*)&vs[0][0];
            int base4 = t0 * (EMB / 4);
            #pragma unroll
            for (int u = 0; u < 4; ++u) {
                int i = t + u * 128;
                int src = base4 + i; if (src > max4) src = max4;
                kd[i] = ksrc[src];
                vd[i] = vsrc[src];
            }
        }
        __syncthreads();

        // float4 key-groups carrying mask: j4 < jm (NODE, t0, valid all
        // multiples of 4 -> groups never straddle the node/patch boundary)
        int jm = 0;
        if (t0 < NODE) {
            int lim = NODE - t0; if (lim > valid) lim = valid;
            jm = lim >> 2;
        }
        float mk0[KT], mk1[KT];
        {
            const float4* mp0 = (const float4*)(mrow0 + t0);
            const float4* mp1 = (const float4*)(mrow1 + t0);
            #pragma unroll
            for (int j4 = 0; j4 < KT / 4; ++j4) {
                float4 a = (j4 < jm) ? mp0[j4] : make_float4(0,0,0,0);
                float4 bm = (j4 < jm) ? mp1[j4] : make_float4(0,0,0,0);
                mk0[4*j4+0]=a.x;  mk0[4*j4+1]=a.y;  mk0[4*j4+2]=a.z;  mk0[4*j4+3]=a.w;
                mk1[4*j4+0]=bm.x; mk1[4*j4+1]=bm.y; mk1[4*j4+2]=bm.z; mk1[4*j4+3]=bm.w;
            }
        }

#define INNER(TAIL)                                                          \
        _Pragma("unroll")                                                    \
        for (int j = 0; j < KT; ++j) {                                       \
            float s0 = mk0[j], s1 = mk1[j];                                  \
            _Pragma("unroll")                                                \
            for (int e = 0; e < DH; e += 4) {                                \
                float4 k4 = *(const float4*)&ks[j][h * DH + e];              \
                s0 += q0[e]*k4.x + q0[e+1]*k4.y + q0[e+2]*k4.z + q0[e+3]*k4.w; \
                s1 += q1r[e]*k4.x + q1r[e+1]*k4.y + q1r[e+2]*k4.z + q1r[e+3]*k4.w; \
            }                                                                \
            float p0 = __expf(s0), p1 = __expf(s1);                          \
            if (TAIL && j >= valid) { p0 = 0.f; p1 = 0.f; }                  \
            l0 += p0; l1 += p1;                                              \
            _Pragma("unroll")                                                \
            for (int e = 0; e < DH; e += 4) {                                \
                float4 v4 = *(const float4*)&vs[j][h * DH + e];              \
                acc0[e+0] += p0*v4.x; acc0[e+1] += p0*v4.y;                  \
                acc0[e+2] += p0*v4.z; acc0[e+3] += p0*v4.w;                  \
                acc1[e+0] += p1*v4.x; acc1[e+1] += p1*v4.y;                  \
                acc1[e+2] += p1*v4.z; acc1[e+3] += p1*v4.w;                  \
            }                                                                \
        }
        __builtin_amdgcn_s_setprio(1);
        if (valid == KT) { INNER(false) } else { INNER(true) }
        __builtin_amdgcn_s_setprio(0);
#undef INNER
    }
    if (active) {
        long cb = ((long)(b * RTILES + tile) * SCH + c);
        // pacc: [cb][row32][h][16] -- dense 64B records, full-line wave stores
        long rec0 = ((cb * TROWS + rr * 2) * NH + h) * 16;
        long rec1 = rec0 + (long)NH * 16;
        #pragma unroll
        for (int i = 0; i < 4; ++i) {
            *(float4*)&pacc[rec0 + 4*i] =
                make_float4(acc0[4*i], acc0[4*i+1], acc0[4*i+2], acc0[4*i+3]);
            *(float4*)&pacc[rec1 + 4*i] =
                make_float4(acc1[4*i], acc1[4*i+1], acc1[4*i+2], acc1[4*i+3]);
        }
        // pl: [cb][h][row32] -- contiguous per (cb,h)
        long plrec = (cb * NH + h) * TROWS + rr * 2;
        *(float2*)&pl[plrec] = make_float2(l0, l1);
    }
}

// ---------------- fused merge + combine: partials -> MH ---------------------
__global__ __launch_bounds__(256) void merge_combine_kernel(
    const float* __restrict__ pacc, const float* __restrict__ pl,
    const float* __restrict__ W5, float* __restrict__ MH)
{
    __shared__ float xs[32][EMB];
    int t = threadIdx.x;
    int b = blockIdx.x, tile = blockIdx.y;
    {   // phase 1: merge
        int rt = t >> 3, h = t & 7;
        int row = tile * TROWS + rt;
        float o[16];
        #pragma unroll
        for (int i = 0; i < 16; ++i) o[i] = 0.f;
        if (row < POMO) {
            long cb0 = (long)(b * RTILES + tile) * SCH;
            const long cs_acc = (long)TROWS * NH * 16;   // 4096 floats/chunk
            long abase = cb0 * cs_acc + ((long)rt * NH + h) * 16;
            const long cs_pl = (long)NH * TROWS;         // 256 floats/chunk
            long lbase = cb0 * cs_pl + (long)h * TROWS + rt;
            float L = 0.f;
            #pragma unroll
            for (int c = 0; c < SCH; ++c) {
                L += pl[lbase + c * cs_pl];
                #pragma unroll
                for (int i4 = 0; i4 < 4; ++i4) {
                    float4 a = *(const float4*)&pacc[abase + c * cs_acc + 4 * i4];
                    o[4*i4+0] += a.x; o[4*i4+1] += a.y;
                    o[4*i4+2] += a.z; o[4*i4+3] += a.w;
                }
            }
            float inv = 1.0f / L;
            #pragma unroll
            for (int i = 0; i < 16; ++i) o[i] *= inv;
        }
        float* xp = &xs[rt][h * DH];
        #pragma unroll
        for (int i4 = 0; i4 < 4; ++i4)
            *(float4*)&xp[4*i4] = make_float4(o[4*i4], o[4*i4+1], o[4*i4+2], o[4*i4+3]);
    }
    __syncthreads();
    {   // phase 2: combine (mh = oc @ Wc.T)
        int o = t & 127;
        int rbase = (t >> 7) * 16;
        const float* W = W5 + 4 * EMB * EMB + o * EMB;
        float acc[16];
        #pragma unroll
        for (int r = 0; r < 16; ++r) acc[r] = 0.f;
        for (int e = 0; e < EMB; e += 4) {
            float4 w4 = *(const float4*)&W[e];
            #pragma unroll
            for (int r = 0; r < 16; ++r) {
                float4 x4 = *(const float4*)&xs[rbase + r][e];
                acc[r] += x4.x * w4.x + x4.y * w4.y + x4.z * w4.z + x4.w * w4.w;
            }
        }
        long row0 = (long)tile * TROWS + rbase;
        #pragma unroll
        for (int r = 0; r < 16; ++r) {
            long row = row0 + r;
            if (row < POMO)
                MH[((long)b * POMO + row) * EMB + o] = acc[r];
        }
    }
}

// ---------------- logits: exp(10*tanh((mh@nodes.T)/sqrt128) + mask) ---------
// 64x128 tile (grid (8,16,8) = 1024 blocks = 4/CU), 4x8 register tile.
// Writes UNNORMALIZED softmax numerators; normalize_kernel divides by sum.
__global__ __launch_bounds__(256, 2) void logits_kernel(
    const float* __restrict__ MH, const float* __restrict__ nodes,
    const float* __restrict__ mask, float* __restrict__ out)
{
    __shared__ float As[32][64];    // [e][n] 8 KB
    __shared__ float Bs[32][192];   // [e][16 groups * 12] 24 KB
    int t = threadIdx.x;
    int b = blockIdx.x;
    int n0 = blockIdx.y * 64;       // pomo rows
    int m0 = blockIdx.z * 128;      // node cols
    int ci = t & 15, ri = t >> 4;

    float acc[4][8];
    #pragma unroll
    for (int i = 0; i < 4; ++i)
        #pragma unroll
        for (int j = 0; j < 8; ++j) acc[i][j] = 0.f;

    // A staging: lnA = row (64), ehA = 8-e group (4 groups)
    int lnA = t & 63;
    int ehA = (t >> 6) * 8;
    int arow = n0 + lnA; if (arow >= POMO) arow = POMO - 1;   // clamp reads
    const float* Arow = MH + ((long)b * POMO + arow) * EMB;
    // B staging: lnB = row (128), ehB = 16-e group (2 groups)
    int lnB = t & 127;
    int ehB = (t >> 7) * 16;
    const float* Brow = nodes + ((long)b * NKEY + m0 + lnB) * EMB;  // m0+127<NKEY
    int bcol = (lnB >> 3) * 12 + (lnB & 7);

    for (int e0 = 0; e0 < EMB; e0 += 32) {
        if (e0) __syncthreads();
        #pragma unroll
        for (int u = 0; u < 2; ++u) {
            int e = ehA + u * 4;
            float4 a4 = *(const float4*)&Arow[e0 + e];
            As[e + 0][lnA] = a4.x; As[e + 1][lnA] = a4.y;
            As[e + 2][lnA] = a4.z; As[e + 3][lnA] = a4.w;
        }
        #pragma unroll
        for (int u = 0; u < 4; ++u) {
            int e = ehB + u * 4;
            float4 b4 = *(const float4*)&Brow[e0 + e];
            Bs[e + 0][bcol] = b4.x; Bs[e + 1][bcol] = b4.y;
            Bs[e + 2][bcol] = b4.z; Bs[e + 3][bcol] = b4.w;
        }
        __syncthreads();
        #pragma unroll
        for (int e = 0; e < 32; ++e) {
            float4 a0 = *(const float4*)&As[e][ri * 4];
            float4 b0 = *(const float4*)&Bs[e][ci * 12];
            float4 b1 = *(const float4*)&Bs[e][ci * 12 + 4];
            float av[4] = {a0.x, a0.y, a0.z, a0.w};
            float bv[8] = {b0.x, b0.y, b0.z, b0.w, b1.x, b1.y, b1.z, b1.w};
            #pragma unroll
            for (int i = 0; i < 4; ++i)
                #pragma unroll
                for (int j = 0; j < 8; ++j)
                    acc[i][j] += av[i] * bv[j];
        }
    }
    const float inv = 0.08838834764831845f;  // 1/sqrt(128)
    bool mfull = (m0 + 127 < NODE);
    int m = m0 + ci * 8;
    #pragma unroll
    for (int i = 0; i < 4; ++i) {
        int n = n0 + ri * 4 + i;
        if (n >= POMO) continue;
        long rbase = ((long)b * POMO + n) * NODE;
        if (mfull) {
            #pragma unroll
            for (int j4 = 0; j4 < 2; ++j4) {
                float4 mk = *(const float4*)&mask[rbase + m + j4 * 4];
                float4 r;
                r.x = __expf(tanh10(acc[i][j4*4+0] * inv) + mk.x);
                r.y = __expf(tanh10(acc[i][j4*4+1] * inv) + mk.y);
                r.z = __expf(tanh10(acc[i][j4*4+2] * inv) + mk.z);
                r.w = __expf(tanh10(acc[i][j4*4+3] * inv) + mk.w);
                *(float4*)&out[rbase + m + j4 * 4] = r;
            }
        } else {
            #pragma unroll
            for (int j = 0; j < 8; ++j) {
                int mm = m + j;
                if (mm < NODE)
                    out[rbase + mm] = __expf(tanh10(acc[i][j] * inv) + mask[rbase + mm]);
            }
        }
    }
}

// ---------------- normalize: divide row by its sum (exp already applied) ----
__global__ __launch_bounds__(256) void normalize_kernel(float* __restrict__ out)
{
    __shared__ float wred[4];
    int t = threadIdx.x;
    int w = t >> 6;
    float* p = out + (long)blockIdx.x * NODE;
    bool act = t < 250;
    float4 x = act ? *(const float4*)&p[t * 4] : make_float4(0.f, 0.f, 0.f, 0.f);
    float sm = x.x + x.y + x.z + x.w;
    #pragma unroll
    for (int s = 32; s >= 1; s >>= 1) sm += __shfl_xor(sm, s);
    if ((t & 63) == 0) wred[w] = sm;
    __syncthreads();
    float inv = 1.0f / (wred[0] + wred[1] + wred[2] + wred[3]);
    if (act) {
        float4 rr;
        rr.x = x.x * inv; rr.y = x.y * inv; rr.z = x.z * inv; rr.w = x.w * inv;
        *(float4*)&p[t * 4] = rr;
    }
}

extern "C" void kernel_launch(void* const* d_in, const int* in_sizes, int n_in,
                              void* d_out, int out_size, void* d_ws, size_t ws_size,
                              hipStream_t stream)
{
    const float* pref  = (const float*)d_in[0];
    const float* nodes = (const float*)d_in[1];
    const float* q1    = (const float*)d_in[2];
    const float* lastn = (const float*)d_in[3];
    const float* mask  = (const float*)d_in[4];
    const float* fc1_w = (const float*)d_in[5];
    const float* fc1_b = (const float*)d_in[6];
    const float* fc2_w = (const float*)d_in[7];
    const float* fc2_b = (const float*)d_in[8];
    const float* fc3_w = (const float*)d_in[9];
    const float* fc3_b = (const float*)d_in[10];
    const float* wqf   = (const float*)d_in[11];
    const float* wql   = (const float*)d_in[12];
    const float* wk    = (const float*)d_in[13];
    const float* wv    = (const float*)d_in[14];
    const float* wc    = (const float*)d_in[15];
    float* out = (float*)d_out;
    float* ws  = (float*)d_ws;

    float* W5 = ws;                                   // 5*16384 = 81920
    float* Kb = ws + 81920;                           // 8*1196*128
    float* Vb = Kb + (long)BB * NKEY * EMB;
    float* Qb = Vb + (long)BB * NKEY * EMB;           // 8*1000*128
    float* MH = Qb + (long)BB * POMO * EMB;
    float* gmid = MH + (long)BB * POMO * EMB;         // 16 floats, ~18.3 MB total

    float* pacc = out;                 // d_out (8M floats) as partial scratch
    float* pl   = out + PACC_FLOATS;   // 7.34M + 0.46M = 7.8M <= 8M; fully
                                       // overwritten by logits afterwards

    hipLaunchKernelGGL(hyper_mid_kernel, dim3(1), dim3(256), 0, stream,
                       pref, fc1_w, fc1_b, fc2_w, fc2_b, fc3_w, fc3_b, gmid);
    hipLaunchKernelGGL(hyper_expand_kernel, dim3(40), dim3(256), 0, stream,
                       gmid, wqf, wql, wk, wv, wc, W5);
    hipLaunchKernelGGL(proj_kernel, dim3(549), dim3(256), 0, stream,
                       nodes, q1, lastn, W5, Kb, Vb, Qb);
    hipLaunchKernelGGL(attn_split_kernel, dim3(8, RTILES, SCH), dim3(128), 0, stream,
                       Kb, Vb, Qb, mask, pacc, pl);
    hipLaunchKernelGGL(merge_combine_kernel, dim3(8, RTILES), dim3(256), 0, stream,
                       pacc, pl, W5, MH);
    hipLaunchKernelGGL(logits_kernel, dim3(8, 16, 8), dim3(256), 0, stream,
                       MH, nodes, mask, out);
    hipLaunchKernelGGL(normalize_kernel, dim3(8000), dim3(256), 0, stream, out);
}